// Round 4
// baseline (85949.384 us; speedup 1.0000x reference)
//
#include <hip/hip_runtime.h>

#define Bz 32
#define Tz 512
#define Dz 512
#define Lz 1024
#define Mz 10
#define G4D 2048
#define KC 128
#define JT 64
#define NKC 8
#define NBLK 256
// k_pre tiles
#define PM 128
#define PN 128
#define PK 32

__device__ __forceinline__ float fsig(float x) { return 1.0f / (1.0f + __expf(-x)); }
__device__ __forceinline__ void st_flag(int* p, int v) {
  __hip_atomic_store(p, v, __ATOMIC_RELEASE, __HIP_MEMORY_SCOPE_AGENT);
}
__device__ __forceinline__ int ld_flag(const int* p) {
  return __hip_atomic_load(p, __ATOMIC_ACQUIRE, __HIP_MEMORY_SCOPE_AGENT);
}

// ---------------- K0 (once): xw[bt][j] = x[bt,:] . W_ih[j,0:512] + b_ih[j] + b_hh[j] ----------------
__global__ __launch_bounds__(256) void k_pre(
    const float* __restrict__ x, const float* __restrict__ W_ih,
    const float* __restrict__ b_ih, const float* __restrict__ b_hh,
    float* __restrict__ xw)
{
  __shared__ float As[PM][PK+1];
  __shared__ float Bs[PN][PK+1];
  const int m0 = blockIdx.x*PM, n0 = blockIdx.y*PN;
  const int tid = threadIdx.x;
  const int mg = tid >> 4, ng = tid & 15;
  float acc[8][8] = {};
  for (int k0 = 0; k0 < Dz; k0 += PK) {
    for (int i = tid; i < PM*(PK/4); i += 256) {
      int row = i >> 3, c4 = (i & 7) << 2;
      float4 v = *reinterpret_cast<const float4*>(&x[(size_t)(m0+row)*Dz + k0 + c4]);
      As[row][c4] = v.x; As[row][c4+1] = v.y; As[row][c4+2] = v.z; As[row][c4+3] = v.w;
    }
    for (int i = tid; i < PN*(PK/4); i += 256) {
      int row = i >> 3, c4 = (i & 7) << 2;
      float4 v = *reinterpret_cast<const float4*>(&W_ih[(size_t)(n0+row)*(2*Dz) + k0 + c4]);
      Bs[row][c4] = v.x; Bs[row][c4+1] = v.y; Bs[row][c4+2] = v.z; Bs[row][c4+3] = v.w;
    }
    __syncthreads();
    #pragma unroll 8
    for (int k = 0; k < PK; k++) {
      float a8[8], b8[8];
      #pragma unroll
      for (int r = 0; r < 8; r++) a8[r] = As[mg*8+r][k];
      #pragma unroll
      for (int s = 0; s < 8; s++) b8[s] = Bs[ng*8+s][k];
      #pragma unroll
      for (int r = 0; r < 8; r++)
        #pragma unroll
        for (int s = 0; s < 8; s++) acc[r][s] += a8[r]*b8[s];
    }
    __syncthreads();
  }
  #pragma unroll
  for (int r = 0; r < 8; r++) {
    int m = m0 + mg*8 + r;
    #pragma unroll
    for (int s = 0; s < 8; s++) {
      int n = n0 + ng*8 + s;
      xw[(size_t)m*G4D + n] = acc[r][s] + b_ih[n] + b_hh[n];
    }
  }
}

// ---------------- Persistent kernel: all 512 steps, flag-based cross-block sync ----------------
// 256 blocks x 256 threads, 1 block/CU guaranteed co-resident (<=54KB LDS).
// A-phase (all blocks): block (jt,kc) computes partial[kc][b][j0..j0+63] over its K-slice.
// B-phase (blocks 0..31): per-batch reduce+LSTM+GMM+attention.
__global__ __launch_bounds__(256) void k_persist(
    const float* __restrict__ memory, const int* __restrict__ lens,
    const float* __restrict__ W_ih, const float* __restrict__ W_hh,
    const float* __restrict__ W_g,  const float* __restrict__ b_g,
    const float* __restrict__ xw,
    float* __restrict__ h, float* __restrict__ ctxs, float* __restrict__ partial,
    int* __restrict__ flagA, int* __restrict__ flagB,
    float* __restrict__ ctx_out, float* __restrict__ align_out,
    float* __restrict__ term_out)
{
  const int blk = blockIdx.x, tid = threadIdx.x;
  const int jt = blk >> 3, kc = blk & 7;
  const int j0 = jt * JT;

  __shared__ float  Ws[JT][KC+2];     // 33.3 KB, weight-stationary across steps
  __shared__ float4 uni4[1040];       // 16.6 KB union: Xs[32][130] | gs[2048] | wsm[1024]
  __shared__ float  hs[Dz];           // 2 KB
  __shared__ float  cs[Dz];           // 2 KB persistent cell state (B blocks)
  __shared__ float  phis[3*Mz], prm[3*Mz];
  __shared__ int    rng[2];

  float (*Xs)[KC+2] = (float(*)[KC+2])uni4;
  float* gs  = (float*)uni4;
  float* wsm = (float*)uni4;

  // ---- stage W tile once (L2-read once; LDS-resident for all 512 steps)
  {
    const float* Wsrc; int ldw, col0;
    if (kc < 4) { Wsrc = W_ih; ldw = 2*Dz; col0 = Dz + kc*KC; }   // ctx part
    else        { Wsrc = W_hh; ldw = Dz;   col0 = (kc-4)*KC; }    // h part
    for (int i = tid; i < JT*(KC/4); i += 256) {
      int jj = i >> 5, k4 = (i & 31) << 2;
      float4 v = *reinterpret_cast<const float4*>(&Wsrc[(size_t)(j0+jj)*ldw + col0 + k4]);
      Ws[jj][k4] = v.x; Ws[jj][k4+1] = v.y; Ws[jj][k4+2] = v.z; Ws[jj][k4+3] = v.w;
    }
  }
  if (blk < Bz) for (int d = tid; d < Dz; d += 256) cs[d] = 0.f;

  for (int t = 0; t < Tz; ++t) {
    // ---- wait for state (ctx,h) of step t-1
    if (t > 0 && tid < Bz) {
      while (ld_flag(&flagB[tid]) < t) __builtin_amdgcn_s_sleep(2);
    }
    __syncthreads();
    __threadfence();   // invalidate stale cached ctx/h (cross-XCD)

    // ---- stage Xs [32][128] (k-slice of [ctx ; h])
    for (int i = tid; i < Bz*(KC/4); i += 256) {
      int bb = i >> 5, k4 = (i & 31) << 2;
      const float* src = (kc < 4) ? &ctxs[bb*Dz + kc*KC + k4]
                                  : &h[bb*Dz + (kc-4)*KC + k4];
      float4 v = *reinterpret_cast<const float4*>(src);
      Xs[bb][k4] = v.x; Xs[bb][k4+1] = v.y; Xs[bb][k4+2] = v.z; Xs[bb][k4+3] = v.w;
    }
    __syncthreads();

    // ---- A compute: thread owns 2 j (stride 32) x 4 b
    {
      const int jg = tid & 31, bl = (tid >> 5) << 2;
      float acc[2][4] = {};
      #pragma unroll 8
      for (int k = 0; k < KC; k += 2) {
        float2 w0 = *reinterpret_cast<const float2*>(&Ws[jg][k]);
        float2 w1 = *reinterpret_cast<const float2*>(&Ws[jg+32][k]);
        #pragma unroll
        for (int bb = 0; bb < 4; bb++) {
          float2 xv = *reinterpret_cast<const float2*>(&Xs[bl+bb][k]);
          acc[0][bb] += w0.x*xv.x + w0.y*xv.y;
          acc[1][bb] += w1.x*xv.x + w1.y*xv.y;
        }
      }
      #pragma unroll
      for (int jj = 0; jj < 2; jj++)
        #pragma unroll
        for (int bb = 0; bb < 4; bb++)
          partial[((size_t)kc*Bz + bl+bb)*G4D + j0 + jg + (jj<<5)] = acc[jj][bb];
    }
    __threadfence();      // make my partial stores agent-visible
    __syncthreads();
    if (tid == 0) st_flag(&flagA[blk], t+1);

    // ---- B phase: blocks 0..31, one batch each
    if (blk < Bz) {
      const int b = blk;
      while (ld_flag(&flagA[tid]) < t+1) __builtin_amdgcn_s_sleep(1);
      __syncthreads();
      __threadfence();    // invalidate stale partials

      // reduce: gates = xw base + 8 K-chunk partials (gs aliases Xs — dead now)
      #pragma unroll
      for (int rep = 0; rep < 2; rep++) {
        int j4 = tid + (rep << 8);
        float4 s = *(reinterpret_cast<const float4*>(&xw[((size_t)b*Tz + t)*G4D]) + j4);
        const float4* pp = reinterpret_cast<const float4*>(partial) + (size_t)b*(G4D/4) + j4;
        #pragma unroll
        for (int k2 = 0; k2 < NKC; k2++) {
          float4 p = pp[(size_t)k2*Bz*(G4D/4)];
          s.x += p.x; s.y += p.y; s.z += p.z; s.w += p.w;
        }
        *(reinterpret_cast<float4*>(gs) + j4) = s;
      }
      __syncthreads();

      // LSTM pointwise, cell state in LDS
      #pragma unroll
      for (int rep = 0; rep < 2; rep++) {
        int d = tid + (rep << 8);
        float ig = 1.0f / (1.0f + expf(-gs[d]));
        float fg = 1.0f / (1.0f + expf(-gs[Dz + d]));
        float gg = tanhf(gs[2*Dz + d]);
        float og = 1.0f / (1.0f + expf(-gs[3*Dz + d]));
        float cn = fg * cs[d] + ig * gg;
        float hn = og * tanhf(cn);
        cs[d] = cn; hs[d] = hn;
        h[b*Dz + d] = hn;     // safe: all A-blocks done reading h(t-1) (flagA wait)
      }
      __syncthreads();

      // phi[m] = hs . W_g[m,:] + b_g[m]  (8 lanes per m)
      if (tid < 8*3*Mz) {
        int m = tid >> 3, l8 = tid & 7;
        float s = 0.f;
        #pragma unroll 8
        for (int k = l8; k < Dz; k += 8) s += W_g[m*Dz + k] * hs[k];
        s += __shfl_xor(s, 1);
        s += __shfl_xor(s, 2);
        s += __shfl_xor(s, 4);
        if (l8 == 0) phis[m] = s + b_g[m];
      }
      __syncthreads();

      // GMM params + active range
      if (tid == 0) {
        float mx = -1e30f;
        #pragma unroll
        for (int m = 0; m < Mz; m++) mx = fmaxf(mx, phis[2*Mz + m]);
        float ae[Mz], ssum = 0.f;
        #pragma unroll
        for (int m = 0; m < Mz; m++) { ae[m] = expf(phis[2*Mz + m] - mx); ssum += ae[m]; }
        float lo = 1e30f, hi = -1e30f;
        #pragma unroll
        for (int m = 0; m < Mz; m++) {
          float ks = expf(phis[m]);
          float be = expf(phis[Mz + m]);
          prm[m]        = ks;
          prm[Mz + m]   = expf(-phis[Mz + m]);
          prm[2*Mz + m] = ae[m] / ssum;
          lo = fminf(lo, ks - 0.5f - 25.f*be);
          hi = fmaxf(hi, ks + 0.5f + 25.f*be);
        }
        int llo = lo > 0.f ? (int)floorf(lo) : 0;
        if (llo > Lz) llo = Lz;
        int lhi = hi < (float)Lz ? (int)ceilf(hi) + 1 : Lz;
        if (lhi > Lz) lhi = Lz;
        rng[0] = llo; rng[1] = lhi;
      }
      __syncthreads();
      const int llo = rng[0], lhi = rng[1];

      // w on active range (wsm aliases gs — gs dead after LSTM)
      for (int l = llo + tid; l < lhi; l += 256) {
        float u = (float)l;
        float t1 = 0.f, t0 = 0.f;
        #pragma unroll
        for (int m = 0; m < Mz; m++) {
          float ks = prm[m], ib = prm[Mz + m], al = prm[2*Mz + m];
          t1 += al * fsig((u + 0.5f - ks) * ib);
          t0 += al * fsig((u - 0.5f - ks) * ib);
        }
        float w = t1 - t0;
        wsm[l] = w;
        align_out[((size_t)b*Tz + t)*Lz + l] = w;
      }
      __syncthreads();

      // ctx einsum over active range, 2 d per thread
      {
        const float* mb = memory + (size_t)b*Lz*Dz;
        float a0 = 0.f, a1 = 0.f;
        for (int l = llo; l < lhi; l++) {
          float w = wsm[l];
          a0 += w * mb[(size_t)l*Dz + tid];
          a1 += w * mb[(size_t)l*Dz + tid + 256];
        }
        ctxs[b*Dz + tid]       = a0;
        ctxs[b*Dz + tid + 256] = a1;
        if (t == Tz-1) {
          ctx_out[b*Dz + tid]       = a0;
          ctx_out[b*Dz + tid + 256] = a1;
          if (tid == 0) {
            float u = (float)(lens[b] - 1);
            float t1 = 0.f;
            #pragma unroll
            for (int m = 0; m < Mz; m++)
              t1 += prm[2*Mz + m] * fsig((u + 0.5f - prm[m]) * prm[Mz + m]);
            term_out[b] = 1.0f - t1;
          }
        }
      }
      __threadfence();
      __syncthreads();
      if (tid == 0) st_flag(&flagB[b], t+1);
    }
  }
}

// ================= fallback (small ws): round-3 two-kernel path =================
__global__ __launch_bounds__(256) void k_gemm(
    const float* __restrict__ x_all, const float* __restrict__ ctxs,
    const float* __restrict__ h, const float* __restrict__ W_ih,
    const float* __restrict__ W_hh, float* __restrict__ partial, int t, int kbase)
{
  __shared__ float Xs[Bz][KC+2];
  __shared__ float Wt[128][KC+2];
  const int jt = blockIdx.x, kcb = blockIdx.y;
  const int j0 = jt*128, k0 = kbase + kcb*KC;
  const int tid = threadIdx.x;
  for (int i = tid; i < Bz*KC; i += 256) {
    int bb = i >> 7, kk = i & (KC-1);
    int k = k0 + kk;
    float v;
    if (k < Dz)        v = x_all[((size_t)bb*Tz + t)*Dz + k];
    else if (k < 2*Dz) v = ctxs[bb*Dz + (k - Dz)];
    else               v = h[bb*Dz + (k - 2*Dz)];
    Xs[bb][kk] = v;
  }
  {
    const float* Wsrc; int ldw, col0;
    if (k0 < 2*Dz) { Wsrc = W_ih; ldw = 2*Dz; col0 = k0; }
    else           { Wsrc = W_hh; ldw = Dz;   col0 = k0 - 2*Dz; }
    for (int i = tid; i < 128*(KC/4); i += 256) {
      int jj = i >> 5, k4 = (i & 31) << 2;
      float4 v = *reinterpret_cast<const float4*>(&Wsrc[(size_t)(j0 + jj)*ldw + col0 + k4]);
      Wt[jj][k4] = v.x; Wt[jj][k4+1] = v.y; Wt[jj][k4+2] = v.z; Wt[jj][k4+3] = v.w;
    }
  }
  __syncthreads();
  const int jg = tid & 31, bg = tid >> 5;
  const int bl = bg << 2;
  float acc[4][4] = {};
  #pragma unroll 4
  for (int k = 0; k < KC; k += 2) {
    float2 xv[4], wv[4];
    #pragma unroll
    for (int bb2 = 0; bb2 < 4; bb2++)
      xv[bb2] = *reinterpret_cast<const float2*>(&Xs[bl + bb2][k]);
    #pragma unroll
    for (int jj = 0; jj < 4; jj++)
      wv[jj] = *reinterpret_cast<const float2*>(&Wt[jg + (jj << 5)][k]);
    #pragma unroll
    for (int jj = 0; jj < 4; jj++)
      #pragma unroll
      for (int bb2 = 0; bb2 < 4; bb2++)
        acc[jj][bb2] += wv[jj].x * xv[bb2].x + wv[jj].y * xv[bb2].y;
  }
  #pragma unroll
  for (int jj = 0; jj < 4; jj++)
    #pragma unroll
    for (int bb2 = 0; bb2 < 4; bb2++)
      partial[((size_t)kcb*Bz + (bl + bb2))*G4D + j0 + jg + (jj << 5)] = acc[jj][bb2];
}

__global__ __launch_bounds__(512) void k_fused(
    const float* __restrict__ partial, const float* __restrict__ b_ih,
    const float* __restrict__ b_hh,
    float* __restrict__ h, float* __restrict__ c,
    const float* __restrict__ W_g, const float* __restrict__ b_g,
    const float* __restrict__ memory, const int* __restrict__ lens,
    float* __restrict__ ctxs, float* __restrict__ ctx_out,
    float* __restrict__ align_out, float* __restrict__ term_out,
    int t, int final_, int nkc)
{
  const int b = blockIdx.x, tid = threadIdx.x;
  __shared__ float4 gs4[G4D/4];
  __shared__ float hsb[Dz];
  __shared__ float phis[3*Mz];
  __shared__ float prm[3*Mz];
  __shared__ float wsm[Lz];
  __shared__ int   rng[2];
  float* gs = (float*)gs4;
  {
    int j = 4*tid;
    float4 bi = *reinterpret_cast<const float4*>(&b_ih[j]);
    float4 bh = *reinterpret_cast<const float4*>(&b_hh[j]);
    float4 s = make_float4(bi.x+bh.x, bi.y+bh.y, bi.z+bh.z, bi.w+bh.w);
    const float4* pp = reinterpret_cast<const float4*>(partial) + (size_t)b*(G4D/4) + tid;
    for (int kcb = 0; kcb < nkc; kcb++) {
      float4 p = pp[(size_t)kcb*Bz*(G4D/4)];
      s.x += p.x; s.y += p.y; s.z += p.z; s.w += p.w;
    }
    gs4[tid] = s;
  }
  __syncthreads();
  {
    const int d = tid;
    float ig = 1.0f / (1.0f + expf(-gs[d]));
    float fg = 1.0f / (1.0f + expf(-gs[Dz + d]));
    float gg = tanhf(gs[2*Dz + d]);
    float og = 1.0f / (1.0f + expf(-gs[3*Dz + d]));
    float cn = fg * c[b*Dz + d] + ig * gg;
    float hn = og * tanhf(cn);
    c[b*Dz + d] = cn;
    h[b*Dz + d] = hn;
    hsb[d] = hn;
  }
  __syncthreads();
  if (tid < 16*3*Mz) {
    int m = tid >> 4, l16 = tid & 15;
    float s = 0.f;
    #pragma unroll 4
    for (int k = l16; k < Dz; k += 16) s += W_g[m*Dz + k] * hsb[k];
    s += __shfl_xor(s, 1);
    s += __shfl_xor(s, 2);
    s += __shfl_xor(s, 4);
    s += __shfl_xor(s, 8);
    if (l16 == 0) phis[m] = s + b_g[m];
  }
  __syncthreads();
  if (tid == 0) {
    float mx = -1e30f;
    #pragma unroll
    for (int m = 0; m < Mz; m++) mx = fmaxf(mx, phis[2*Mz + m]);
    float ae[Mz], ssum = 0.f;
    #pragma unroll
    for (int m = 0; m < Mz; m++) { ae[m] = expf(phis[2*Mz + m] - mx); ssum += ae[m]; }
    float lo = 1e30f, hi = -1e30f;
    #pragma unroll
    for (int m = 0; m < Mz; m++) {
      float ks = expf(phis[m]);
      float be = expf(phis[Mz + m]);
      prm[m]        = ks;
      prm[Mz + m]   = expf(-phis[Mz + m]);
      prm[2*Mz + m] = ae[m] / ssum;
      lo = fminf(lo, ks - 0.5f - 25.f*be);
      hi = fmaxf(hi, ks + 0.5f + 25.f*be);
    }
    int llo = lo > 0.f ? (int)floorf(lo) : 0;
    if (llo > Lz) llo = Lz;
    int lhi = hi < (float)Lz ? (int)ceilf(hi) + 1 : Lz;
    if (lhi > Lz) lhi = Lz;
    rng[0] = llo; rng[1] = lhi;
  }
  __syncthreads();
  const int llo = rng[0], lhi = rng[1];
  for (int l = llo + tid; l < lhi; l += 512) {
    float u = (float)l;
    float t1 = 0.f, t0 = 0.f;
    #pragma unroll
    for (int m = 0; m < Mz; m++) {
      float ks = prm[m], ib = prm[Mz + m], al = prm[2*Mz + m];
      t1 += al * fsig((u + 0.5f - ks) * ib);
      t0 += al * fsig((u - 0.5f - ks) * ib);
    }
    float w = t1 - t0;
    wsm[l] = w;
    align_out[((size_t)b*Tz + t)*Lz + l] = w;
  }
  __syncthreads();
  {
    const float* mb = memory + (size_t)b*Lz*Dz + tid;
    float acc = 0.f;
    #pragma unroll 4
    for (int l = llo; l < lhi; l++)
      acc += wsm[l] * mb[(size_t)l*Dz];
    ctxs[b*Dz + tid] = acc;
    if (final_) ctx_out[b*Dz + tid] = acc;
  }
  if (final_ && tid == 0) {
    float u = (float)(lens[b] - 1);
    float t1 = 0.f;
    #pragma unroll
    for (int m = 0; m < Mz; m++)
      t1 += prm[2*Mz + m] * fsig((u + 0.5f - prm[m]) * prm[Mz + m]);
    term_out[b] = 1.0f - t1;
  }
}

extern "C" void kernel_launch(void* const* d_in, const int* in_sizes, int n_in,
                              void* d_out, int out_size, void* d_ws, size_t ws_size,
                              hipStream_t stream)
{
  (void)in_sizes; (void)n_in; (void)out_size;
  const float* x    = (const float*)d_in[0];
  const float* mem  = (const float*)d_in[1];
  const int*   lens = (const int*)d_in[2];
  const float* W_ih = (const float*)d_in[3];
  const float* W_hh = (const float*)d_in[4];
  const float* b_ih = (const float*)d_in[5];
  const float* b_hh = (const float*)d_in[6];
  const float* W_g  = (const float*)d_in[7];
  const float* b_g  = (const float*)d_in[8];

  float* out = (float*)d_out;
  float* ctx_out   = out;                                  // [B,1,D]
  float* align_out = out + Bz*Dz;                          // [B,T,L]
  float* term_out  = out + Bz*Dz + (size_t)Bz*Tz*Lz;       // [B,1]

  // persistent path ws layout
  const size_t needP = ((size_t)512 + 2*Bz*Dz + (size_t)NKC*Bz*G4D
                        + (size_t)Bz*Tz*G4D) * sizeof(float);

  hipMemsetAsync(align_out, 0, (size_t)Bz*Tz*Lz*sizeof(float), stream);

  if (ws_size >= needP) {
    int*   flagA   = (int*)d_ws;                 // [256]
    int*   flagB   = flagA + NBLK;               // [32] (padded region to 512 ints)
    float* h       = (float*)d_ws + 512;         // [B,D]
    float* ctxs    = h + Bz*Dz;                  // [B,D]
    float* partial = ctxs + Bz*Dz;               // [8][B][4D]
    float* xw      = partial + (size_t)NKC*Bz*G4D; // [B*T][4D]

    // zero flags + h + ctx
    hipMemsetAsync(d_ws, 0, (size_t)(512 + 2*Bz*Dz)*sizeof(float), stream);
    k_pre<<<dim3((Bz*Tz)/PM, G4D/PN), 256, 0, stream>>>(x, W_ih, b_ih, b_hh, xw);
    k_persist<<<NBLK, 256, 0, stream>>>(mem, lens, W_ih, W_hh, W_g, b_g, xw,
                                        h, ctxs, partial, flagA, flagB,
                                        ctx_out, align_out, term_out);
  } else {
    float* wsf     = (float*)d_ws;
    float* h       = wsf;
    float* c       = h + Bz*Dz;
    float* ctxs    = c + Bz*Dz;
    float* partial = ctxs + Bz*Dz;               // [12][B][4D]
    hipMemsetAsync(d_ws, 0, (size_t)(3*Bz*Dz)*sizeof(float), stream);
    for (int t = 0; t < Tz; t++) {
      k_gemm<<<dim3(G4D/128, 12), 256, 0, stream>>>(x, ctxs, h, W_ih, W_hh, partial, t, 0);
      k_fused<<<Bz, 512, 0, stream>>>(partial, b_ih, b_hh, h, c, W_g, b_g,
                                      mem, lens, ctxs, ctx_out, align_out, term_out,
                                      t, t == Tz-1, 12);
    }
  }
}

// Round 5
// 13842.072 us; speedup vs baseline: 6.2093x; 6.2093x over previous
//
#include <hip/hip_runtime.h>

#define Bz 32
#define Tz 512
#define Dz 512
#define Lz 1024
#define Mz 10
#define G4D 2048
#define KC 128
#define JT 64
#define NKC 8
#define NBLK 256
// k_pre tiles
#define PM 128
#define PN 128
#define PK 32

__device__ __forceinline__ float fsig(float x) { return 1.0f / (1.0f + __expf(-x)); }

// ---- cross-block comm: RELAXED agent-scope atomics (lower to sc1 loads/stores
// that bypass L1/L2 to the device coherent point; NO cache-maintenance ops) ----
__device__ __forceinline__ void st_rlx(int* p, int v) {
  __hip_atomic_store(p, v, __ATOMIC_RELAXED, __HIP_MEMORY_SCOPE_AGENT);
}
__device__ __forceinline__ int ld_rlx(const int* p) {
  return __hip_atomic_load(p, __ATOMIC_RELAXED, __HIP_MEMORY_SCOPE_AGENT);
}
__device__ __forceinline__ void cstore(float* p, float v) {
  __hip_atomic_store(p, v, __ATOMIC_RELAXED, __HIP_MEMORY_SCOPE_AGENT);
}
__device__ __forceinline__ float cload(const float* p) {
  return __hip_atomic_load(p, __ATOMIC_RELAXED, __HIP_MEMORY_SCOPE_AGENT);
}

// ---------------- K0 (once): xw[bt][j] = x[bt,:] . W_ih[j,0:512] + b_ih[j] + b_hh[j] ----------------
__global__ __launch_bounds__(256) void k_pre(
    const float* __restrict__ x, const float* __restrict__ W_ih,
    const float* __restrict__ b_ih, const float* __restrict__ b_hh,
    float* __restrict__ xw)
{
  __shared__ float As[PM][PK+1];
  __shared__ float Bs[PN][PK+1];
  const int m0 = blockIdx.x*PM, n0 = blockIdx.y*PN;
  const int tid = threadIdx.x;
  const int mg = tid >> 4, ng = tid & 15;
  float acc[8][8] = {};
  for (int k0 = 0; k0 < Dz; k0 += PK) {
    for (int i = tid; i < PM*(PK/4); i += 256) {
      int row = i >> 3, c4 = (i & 7) << 2;
      float4 v = *reinterpret_cast<const float4*>(&x[(size_t)(m0+row)*Dz + k0 + c4]);
      As[row][c4] = v.x; As[row][c4+1] = v.y; As[row][c4+2] = v.z; As[row][c4+3] = v.w;
    }
    for (int i = tid; i < PN*(PK/4); i += 256) {
      int row = i >> 3, c4 = (i & 7) << 2;
      float4 v = *reinterpret_cast<const float4*>(&W_ih[(size_t)(n0+row)*(2*Dz) + k0 + c4]);
      Bs[row][c4] = v.x; Bs[row][c4+1] = v.y; Bs[row][c4+2] = v.z; Bs[row][c4+3] = v.w;
    }
    __syncthreads();
    #pragma unroll 8
    for (int k = 0; k < PK; k++) {
      float a8[8], b8[8];
      #pragma unroll
      for (int r = 0; r < 8; r++) a8[r] = As[mg*8+r][k];
      #pragma unroll
      for (int s = 0; s < 8; s++) b8[s] = Bs[ng*8+s][k];
      #pragma unroll
      for (int r = 0; r < 8; r++)
        #pragma unroll
        for (int s = 0; s < 8; s++) acc[r][s] += a8[r]*b8[s];
    }
    __syncthreads();
  }
  #pragma unroll
  for (int r = 0; r < 8; r++) {
    int m = m0 + mg*8 + r;
    #pragma unroll
    for (int s = 0; s < 8; s++) {
      int n = n0 + ng*8 + s;
      xw[(size_t)m*G4D + n] = acc[r][s] + b_ih[n] + b_hh[n];
    }
  }
}

// ---------------- Persistent kernel: all 512 steps, relaxed-sc1 flag sync ----------------
__global__ __launch_bounds__(256) void k_persist(
    const float* __restrict__ memory, const int* __restrict__ lens,
    const float* __restrict__ W_ih, const float* __restrict__ W_hh,
    const float* __restrict__ W_g,  const float* __restrict__ b_g,
    const float* __restrict__ xw,
    float* __restrict__ h, float* __restrict__ ctxs, float* __restrict__ partial,
    int* __restrict__ flagA, int* __restrict__ flagB,
    float* __restrict__ ctx_out, float* __restrict__ align_out,
    float* __restrict__ term_out)
{
  const int blk = blockIdx.x, tid = threadIdx.x;
  const int jt = blk >> 3, kc = blk & 7;
  const int j0 = jt * JT;

  __shared__ float  Ws[JT][KC+2];     // 33.3 KB, weight-stationary across steps
  __shared__ float4 uni4[1040];       // 16.6 KB union: Xs[32][130] | gs[2048] | wsm[1024]
  __shared__ float  hs[Dz];           // 2 KB
  __shared__ float  cs[Dz];           // 2 KB persistent cell state (B blocks)
  __shared__ float  phis[3*Mz], prm[3*Mz];
  __shared__ int    rng[2];

  float (*Xs)[KC+2] = (float(*)[KC+2])uni4;
  float* gs  = (float*)uni4;
  float* wsm = (float*)uni4;

  // ---- stage W tile once (read once; LDS-resident for all 512 steps)
  {
    const float* Wsrc; int ldw, col0;
    if (kc < 4) { Wsrc = W_ih; ldw = 2*Dz; col0 = Dz + kc*KC; }   // ctx part
    else        { Wsrc = W_hh; ldw = Dz;   col0 = (kc-4)*KC; }    // h part
    for (int i = tid; i < JT*(KC/4); i += 256) {
      int jj = i >> 5, k4 = (i & 31) << 2;
      float4 v = *reinterpret_cast<const float4*>(&Wsrc[(size_t)(j0+jj)*ldw + col0 + k4]);
      Ws[jj][k4] = v.x; Ws[jj][k4+1] = v.y; Ws[jj][k4+2] = v.z; Ws[jj][k4+3] = v.w;
    }
  }
  if (blk < Bz) for (int d = tid; d < Dz; d += 256) cs[d] = 0.f;

  for (int t = 0; t < Tz; ++t) {
    // ---- wait for state (ctx,h) of step t-1 (relaxed LLC polls - cheap)
    if (t > 0 && tid < Bz) {
      while (ld_rlx(&flagB[tid]) < t) __builtin_amdgcn_s_sleep(1);
    }
    __syncthreads();

    // ---- stage Xs [32][128] (k-slice of [ctx ; h]) via sc1 loads (always fresh)
    for (int i = tid; i < Bz*KC; i += 256) {
      int bb = i >> 7, kk = i & (KC-1);
      const float* src = (kc < 4) ? &ctxs[bb*Dz + kc*KC + kk]
                                  : &h[bb*Dz + (kc-4)*KC + kk];
      Xs[bb][kk] = cload(src);
    }
    __syncthreads();

    // ---- A compute: thread owns 2 j (stride 32) x 4 b
    {
      const int jg = tid & 31, bl = (tid >> 5) << 2;
      float acc[2][4] = {};
      #pragma unroll 8
      for (int k = 0; k < KC; k += 2) {
        float2 w0 = *reinterpret_cast<const float2*>(&Ws[jg][k]);
        float2 w1 = *reinterpret_cast<const float2*>(&Ws[jg+32][k]);
        #pragma unroll
        for (int bb = 0; bb < 4; bb++) {
          float2 xv = *reinterpret_cast<const float2*>(&Xs[bl+bb][k]);
          acc[0][bb] += w0.x*xv.x + w0.y*xv.y;
          acc[1][bb] += w1.x*xv.x + w1.y*xv.y;
        }
      }
      #pragma unroll
      for (int jj = 0; jj < 2; jj++)
        #pragma unroll
        for (int bb = 0; bb < 4; bb++)
          cstore(&partial[((size_t)kc*Bz + bl+bb)*G4D + j0 + jg + (jj<<5)], acc[jj][bb]);
    }
    __syncthreads();               // drains vmcnt(0): partials at LLC
    if (tid == 0) {
      asm volatile("s_waitcnt vmcnt(0)" ::: "memory");
      st_rlx(&flagA[blk], t+1);
    }

    // ---- B phase: blocks 0..31, one batch each
    if (blk < Bz) {
      const int b = blk;
      while (ld_rlx(&flagA[tid]) < t+1) __builtin_amdgcn_s_sleep(1);
      __syncthreads();

      // reduce: gates = xw base + 8 K-chunk partials (gs aliases Xs - dead now)
      #pragma unroll
      for (int rep = 0; rep < 8; rep++) {
        int j = (rep << 8) + tid;
        float s = xw[((size_t)b*Tz + t)*G4D + j];
        #pragma unroll
        for (int k2 = 0; k2 < NKC; k2++)
          s += cload(&partial[((size_t)k2*Bz + b)*G4D + j]);
        gs[j] = s;
      }
      __syncthreads();

      // LSTM pointwise, cell state in LDS
      #pragma unroll
      for (int rep = 0; rep < 2; rep++) {
        int d = tid + (rep << 8);
        float ig = 1.0f / (1.0f + expf(-gs[d]));
        float fg = 1.0f / (1.0f + expf(-gs[Dz + d]));
        float gg = tanhf(gs[2*Dz + d]);
        float og = 1.0f / (1.0f + expf(-gs[3*Dz + d]));
        float cn = fg * cs[d] + ig * gg;
        float hn = og * tanhf(cn);
        cs[d] = cn; hs[d] = hn;
        cstore(&h[b*Dz + d], hn);   // safe: all A-blocks done reading h(t-1)
      }
      __syncthreads();

      // phi[m] = hs . W_g[m,:] + b_g[m]  (8 lanes per m; W_g stays L1/L2-hot)
      if (tid < 8*3*Mz) {
        int m = tid >> 3, l8 = tid & 7;
        float s = 0.f;
        #pragma unroll 8
        for (int k = l8; k < Dz; k += 8) s += W_g[m*Dz + k] * hs[k];
        s += __shfl_xor(s, 1);
        s += __shfl_xor(s, 2);
        s += __shfl_xor(s, 4);
        if (l8 == 0) phis[m] = s + b_g[m];
      }
      __syncthreads();

      // GMM params + active range
      if (tid == 0) {
        float mx = -1e30f;
        #pragma unroll
        for (int m = 0; m < Mz; m++) mx = fmaxf(mx, phis[2*Mz + m]);
        float ae[Mz], ssum = 0.f;
        #pragma unroll
        for (int m = 0; m < Mz; m++) { ae[m] = expf(phis[2*Mz + m] - mx); ssum += ae[m]; }
        float lo = 1e30f, hi = -1e30f;
        #pragma unroll
        for (int m = 0; m < Mz; m++) {
          float ks = expf(phis[m]);
          float be = expf(phis[Mz + m]);
          prm[m]        = ks;
          prm[Mz + m]   = expf(-phis[Mz + m]);
          prm[2*Mz + m] = ae[m] / ssum;
          lo = fminf(lo, ks - 0.5f - 25.f*be);   // sig(-25) below fp32 visibility
          hi = fmaxf(hi, ks + 0.5f + 25.f*be);
        }
        int llo = lo > 0.f ? (int)floorf(lo) : 0;
        if (llo > Lz) llo = Lz;
        int lhi = hi < (float)Lz ? (int)ceilf(hi) + 1 : Lz;
        if (lhi > Lz) lhi = Lz;
        rng[0] = llo; rng[1] = lhi;
      }
      __syncthreads();
      const int llo = rng[0], lhi = rng[1];

      // w on active range (wsm aliases gs - gs dead after LSTM)
      for (int l = llo + tid; l < lhi; l += 256) {
        float u = (float)l;
        float t1 = 0.f, t0 = 0.f;
        #pragma unroll
        for (int m = 0; m < Mz; m++) {
          float ks = prm[m], ib = prm[Mz + m], al = prm[2*Mz + m];
          t1 += al * fsig((u + 0.5f - ks) * ib);
          t0 += al * fsig((u - 0.5f - ks) * ib);
        }
        float w = t1 - t0;
        wsm[l] = w;
        align_out[((size_t)b*Tz + t)*Lz + l] = w;
      }
      __syncthreads();

      // ctx einsum over active range, 2 d per thread (memory slab L2-hot)
      {
        const float* mb = memory + (size_t)b*Lz*Dz;
        float a0 = 0.f, a1 = 0.f;
        for (int l = llo; l < lhi; l++) {
          float w = wsm[l];
          a0 += w * mb[(size_t)l*Dz + tid];
          a1 += w * mb[(size_t)l*Dz + tid + 256];
        }
        cstore(&ctxs[b*Dz + tid],       a0);
        cstore(&ctxs[b*Dz + tid + 256], a1);
        if (t == Tz-1) {
          ctx_out[b*Dz + tid]       = a0;
          ctx_out[b*Dz + tid + 256] = a1;
          if (tid == 0) {
            float u = (float)(lens[b] - 1);
            float t1 = 0.f;
            #pragma unroll
            for (int m = 0; m < Mz; m++)
              t1 += prm[2*Mz + m] * fsig((u + 0.5f - prm[m]) * prm[Mz + m]);
            term_out[b] = 1.0f - t1;
          }
        }
      }
      __syncthreads();             // drains vmcnt(0): h/ctx at LLC
      if (tid == 0) {
        asm volatile("s_waitcnt vmcnt(0)" ::: "memory");
        st_rlx(&flagB[b], t+1);
      }
    }
  }
}

// ================= fallback (small ws): two-kernel loop path =================
__global__ __launch_bounds__(256) void k_gemm(
    const float* __restrict__ x_all, const float* __restrict__ ctxs,
    const float* __restrict__ h, const float* __restrict__ W_ih,
    const float* __restrict__ W_hh, float* __restrict__ partial, int t, int kbase)
{
  __shared__ float Xs[Bz][KC+2];
  __shared__ float Wt[128][KC+2];
  const int jt = blockIdx.x, kcb = blockIdx.y;
  const int j0 = jt*128, k0 = kbase + kcb*KC;
  const int tid = threadIdx.x;
  for (int i = tid; i < Bz*KC; i += 256) {
    int bb = i >> 7, kk = i & (KC-1);
    int k = k0 + kk;
    float v;
    if (k < Dz)        v = x_all[((size_t)bb*Tz + t)*Dz + k];
    else if (k < 2*Dz) v = ctxs[bb*Dz + (k - Dz)];
    else               v = h[bb*Dz + (k - 2*Dz)];
    Xs[bb][kk] = v;
  }
  {
    const float* Wsrc; int ldw, col0;
    if (k0 < 2*Dz) { Wsrc = W_ih; ldw = 2*Dz; col0 = k0; }
    else           { Wsrc = W_hh; ldw = Dz;   col0 = k0 - 2*Dz; }
    for (int i = tid; i < 128*(KC/4); i += 256) {
      int jj = i >> 5, k4 = (i & 31) << 2;
      float4 v = *reinterpret_cast<const float4*>(&Wsrc[(size_t)(j0 + jj)*ldw + col0 + k4]);
      Wt[jj][k4] = v.x; Wt[jj][k4+1] = v.y; Wt[jj][k4+2] = v.z; Wt[jj][k4+3] = v.w;
    }
  }
  __syncthreads();
  const int jg = tid & 31, bg = tid >> 5;
  const int bl = bg << 2;
  float acc[4][4] = {};
  #pragma unroll 4
  for (int k = 0; k < KC; k += 2) {
    float2 xv[4], wv[4];
    #pragma unroll
    for (int bb2 = 0; bb2 < 4; bb2++)
      xv[bb2] = *reinterpret_cast<const float2*>(&Xs[bl + bb2][k]);
    #pragma unroll
    for (int jj = 0; jj < 4; jj++)
      wv[jj] = *reinterpret_cast<const float2*>(&Wt[jg + (jj << 5)][k]);
    #pragma unroll
    for (int jj = 0; jj < 4; jj++)
      #pragma unroll
      for (int bb2 = 0; bb2 < 4; bb2++)
        acc[jj][bb2] += wv[jj].x * xv[bb2].x + wv[jj].y * xv[bb2].y;
  }
  #pragma unroll
  for (int jj = 0; jj < 4; jj++)
    #pragma unroll
    for (int bb2 = 0; bb2 < 4; bb2++)
      partial[((size_t)kcb*Bz + (bl + bb2))*G4D + j0 + jg + (jj << 5)] = acc[jj][bb2];
}

__global__ __launch_bounds__(512) void k_fused(
    const float* __restrict__ partial, const float* __restrict__ b_ih,
    const float* __restrict__ b_hh,
    float* __restrict__ h, float* __restrict__ c,
    const float* __restrict__ W_g, const float* __restrict__ b_g,
    const float* __restrict__ memory, const int* __restrict__ lens,
    float* __restrict__ ctxs, float* __restrict__ ctx_out,
    float* __restrict__ align_out, float* __restrict__ term_out,
    int t, int final_, int nkc)
{
  const int b = blockIdx.x, tid = threadIdx.x;
  __shared__ float4 gs4[G4D/4];
  __shared__ float hsb[Dz];
  __shared__ float phis[3*Mz];
  __shared__ float prm[3*Mz];
  __shared__ float wsm[Lz];
  __shared__ int   rng[2];
  float* gs = (float*)gs4;
  {
    int j = 4*tid;
    float4 bi = *reinterpret_cast<const float4*>(&b_ih[j]);
    float4 bh = *reinterpret_cast<const float4*>(&b_hh[j]);
    float4 s = make_float4(bi.x+bh.x, bi.y+bh.y, bi.z+bh.z, bi.w+bh.w);
    const float4* pp = reinterpret_cast<const float4*>(partial) + (size_t)b*(G4D/4) + tid;
    for (int kcb = 0; kcb < nkc; kcb++) {
      float4 p = pp[(size_t)kcb*Bz*(G4D/4)];
      s.x += p.x; s.y += p.y; s.z += p.z; s.w += p.w;
    }
    gs4[tid] = s;
  }
  __syncthreads();
  {
    const int d = tid;
    float ig = 1.0f / (1.0f + expf(-gs[d]));
    float fg = 1.0f / (1.0f + expf(-gs[Dz + d]));
    float gg = tanhf(gs[2*Dz + d]);
    float og = 1.0f / (1.0f + expf(-gs[3*Dz + d]));
    float cn = fg * c[b*Dz + d] + ig * gg;
    float hn = og * tanhf(cn);
    c[b*Dz + d] = cn;
    h[b*Dz + d] = hn;
    hsb[d] = hn;
  }
  __syncthreads();
  if (tid < 16*3*Mz) {
    int m = tid >> 4, l16 = tid & 15;
    float s = 0.f;
    #pragma unroll 4
    for (int k = l16; k < Dz; k += 16) s += W_g[m*Dz + k] * hsb[k];
    s += __shfl_xor(s, 1);
    s += __shfl_xor(s, 2);
    s += __shfl_xor(s, 4);
    s += __shfl_xor(s, 8);
    if (l16 == 0) phis[m] = s + b_g[m];
  }
  __syncthreads();
  if (tid == 0) {
    float mx = -1e30f;
    #pragma unroll
    for (int m = 0; m < Mz; m++) mx = fmaxf(mx, phis[2*Mz + m]);
    float ae[Mz], ssum = 0.f;
    #pragma unroll
    for (int m = 0; m < Mz; m++) { ae[m] = expf(phis[2*Mz + m] - mx); ssum += ae[m]; }
    float lo = 1e30f, hi = -1e30f;
    #pragma unroll
    for (int m = 0; m < Mz; m++) {
      float ks = expf(phis[m]);
      float be = expf(phis[Mz + m]);
      prm[m]        = ks;
      prm[Mz + m]   = expf(-phis[Mz + m]);
      prm[2*Mz + m] = ae[m] / ssum;
      lo = fminf(lo, ks - 0.5f - 25.f*be);
      hi = fmaxf(hi, ks + 0.5f + 25.f*be);
    }
    int llo = lo > 0.f ? (int)floorf(lo) : 0;
    if (llo > Lz) llo = Lz;
    int lhi = hi < (float)Lz ? (int)ceilf(hi) + 1 : Lz;
    if (lhi > Lz) lhi = Lz;
    rng[0] = llo; rng[1] = lhi;
  }
  __syncthreads();
  const int llo = rng[0], lhi = rng[1];
  for (int l = llo + tid; l < lhi; l += 512) {
    float u = (float)l;
    float t1 = 0.f, t0 = 0.f;
    #pragma unroll
    for (int m = 0; m < Mz; m++) {
      float ks = prm[m], ib = prm[Mz + m], al = prm[2*Mz + m];
      t1 += al * fsig((u + 0.5f - ks) * ib);
      t0 += al * fsig((u - 0.5f - ks) * ib);
    }
    float w = t1 - t0;
    wsm[l] = w;
    align_out[((size_t)b*Tz + t)*Lz + l] = w;
  }
  __syncthreads();
  {
    const float* mb = memory + (size_t)b*Lz*Dz + tid;
    float acc = 0.f;
    #pragma unroll 4
    for (int l = llo; l < lhi; l++)
      acc += wsm[l] * mb[(size_t)l*Dz];
    ctxs[b*Dz + tid] = acc;
    if (final_) ctx_out[b*Dz + tid] = acc;
  }
  if (final_ && tid == 0) {
    float u = (float)(lens[b] - 1);
    float t1 = 0.f;
    #pragma unroll
    for (int m = 0; m < Mz; m++)
      t1 += prm[2*Mz + m] * fsig((u + 0.5f - prm[m]) * prm[Mz + m]);
    term_out[b] = 1.0f - t1;
  }
}

extern "C" void kernel_launch(void* const* d_in, const int* in_sizes, int n_in,
                              void* d_out, int out_size, void* d_ws, size_t ws_size,
                              hipStream_t stream)
{
  (void)in_sizes; (void)n_in; (void)out_size;
  const float* x    = (const float*)d_in[0];
  const float* mem  = (const float*)d_in[1];
  const int*   lens = (const int*)d_in[2];
  const float* W_ih = (const float*)d_in[3];
  const float* W_hh = (const float*)d_in[4];
  const float* b_ih = (const float*)d_in[5];
  const float* b_hh = (const float*)d_in[6];
  const float* W_g  = (const float*)d_in[7];
  const float* b_g  = (const float*)d_in[8];

  float* out = (float*)d_out;
  float* ctx_out   = out;                                  // [B,1,D]
  float* align_out = out + Bz*Dz;                          // [B,T,L]
  float* term_out  = out + Bz*Dz + (size_t)Bz*Tz*Lz;       // [B,1]

  const size_t needP = ((size_t)512 + 2*Bz*Dz + (size_t)NKC*Bz*G4D
                        + (size_t)Bz*Tz*G4D) * sizeof(float);

  hipMemsetAsync(align_out, 0, (size_t)Bz*Tz*Lz*sizeof(float), stream);

  if (ws_size >= needP) {
    int*   flagA   = (int*)d_ws;                 // [256]
    int*   flagB   = flagA + NBLK;               // [32] (region padded to 512 ints)
    float* h       = (float*)d_ws + 512;         // [B,D]
    float* ctxs    = h + Bz*Dz;                  // [B,D]
    float* partial = ctxs + Bz*Dz;               // [8][B][4D]
    float* xw      = partial + (size_t)NKC*Bz*G4D; // [B*T][4D]

    hipMemsetAsync(d_ws, 0, (size_t)(512 + 2*Bz*Dz)*sizeof(float), stream);
    k_pre<<<dim3((Bz*Tz)/PM, G4D/PN), 256, 0, stream>>>(x, W_ih, b_ih, b_hh, xw);
    k_persist<<<NBLK, 256, 0, stream>>>(mem, lens, W_ih, W_hh, W_g, b_g, xw,
                                        h, ctxs, partial, flagA, flagB,
                                        ctx_out, align_out, term_out);
  } else {
    float* wsf     = (float*)d_ws;
    float* h       = wsf;
    float* c       = h + Bz*Dz;
    float* ctxs    = c + Bz*Dz;
    float* partial = ctxs + Bz*Dz;               // [12][B][4D]
    hipMemsetAsync(d_ws, 0, (size_t)(3*Bz*Dz)*sizeof(float), stream);
    for (int t = 0; t < Tz; t++) {
      k_gemm<<<dim3(G4D/128, 12), 256, 0, stream>>>(x, ctxs, h, W_ih, W_hh, partial, t, 0);
      k_fused<<<Bz, 512, 0, stream>>>(partial, b_ih, b_hh, h, c, W_g, b_g,
                                      mem, lens, ctxs, ctx_out, align_out, term_out,
                                      t, t == Tz-1, 12);
    }
  }
}

// Round 6
// 10472.425 us; speedup vs baseline: 8.2072x; 1.3218x over previous
//
#include <hip/hip_runtime.h>

#define Bz 32
#define Tz 512
#define Dz 512
#define Lz 1024
#define Mz 10
#define G4D 2048
#define KC 128
#define JT 64
#define NKC 8
#define NBLK 256
#define FP 32                 // ints per flag slot (128B line padding)
#define NFLA (NBLK*FP)        // 8192 ints
#define NFLH (Bz*FP)          // 1024 ints
#define NFLAGS (NFLA + 2*NFLH) // 10240 ints
// k_pre tiles
#define PM 128
#define PN 128
#define PK 32

__device__ __forceinline__ float fsig(float x) { return 1.0f / (1.0f + __expf(-x)); }

// ---- cross-block comm: RELAXED agent-scope atomics (sc-flagged, bypass L1/L2
// to the device coherence point; no cache-maintenance instructions) ----
__device__ __forceinline__ void st_rlx(int* p, int v) {
  __hip_atomic_store(p, v, __ATOMIC_RELAXED, __HIP_MEMORY_SCOPE_AGENT);
}
__device__ __forceinline__ int ld_rlx(const int* p) {
  return __hip_atomic_load(p, __ATOMIC_RELAXED, __HIP_MEMORY_SCOPE_AGENT);
}
__device__ __forceinline__ void st_rlx64(unsigned long long* p, unsigned long long v) {
  __hip_atomic_store(p, v, __ATOMIC_RELAXED, __HIP_MEMORY_SCOPE_AGENT);
}
__device__ __forceinline__ unsigned long long ld_rlx64(const unsigned long long* p) {
  return __hip_atomic_load(p, __ATOMIC_RELAXED, __HIP_MEMORY_SCOPE_AGENT);
}
__device__ __forceinline__ void cstore(float* p, float v) {
  __hip_atomic_store(p, v, __ATOMIC_RELAXED, __HIP_MEMORY_SCOPE_AGENT);
}
__device__ __forceinline__ unsigned long long pack2(float a, float b) {
  union { float f[2]; unsigned long long u; } z; z.f[0] = a; z.f[1] = b; return z.u;
}
__device__ __forceinline__ float2 unpack2(unsigned long long u) {
  union { unsigned long long uu; float2 f; } z; z.uu = u; return z.f;
}
#define VWAIT() asm volatile("s_waitcnt vmcnt(0)" ::: "memory")

// ---------------- K0 (once): xw[bt][j] = x[bt,:] . W_ih[j,0:512] + b_ih[j] + b_hh[j] ----------------
__global__ __launch_bounds__(256) void k_pre(
    const float* __restrict__ x, const float* __restrict__ W_ih,
    const float* __restrict__ b_ih, const float* __restrict__ b_hh,
    float* __restrict__ xw)
{
  __shared__ float As[PM][PK+1];
  __shared__ float Bs[PN][PK+1];
  const int m0 = blockIdx.x*PM, n0 = blockIdx.y*PN;
  const int tid = threadIdx.x;
  const int mg = tid >> 4, ng = tid & 15;
  float acc[8][8] = {};
  for (int k0 = 0; k0 < Dz; k0 += PK) {
    for (int i = tid; i < PM*(PK/4); i += 256) {
      int row = i >> 3, c4 = (i & 7) << 2;
      float4 v = *reinterpret_cast<const float4*>(&x[(size_t)(m0+row)*Dz + k0 + c4]);
      As[row][c4] = v.x; As[row][c4+1] = v.y; As[row][c4+2] = v.z; As[row][c4+3] = v.w;
    }
    for (int i = tid; i < PN*(PK/4); i += 256) {
      int row = i >> 3, c4 = (i & 7) << 2;
      float4 v = *reinterpret_cast<const float4*>(&W_ih[(size_t)(n0+row)*(2*Dz) + k0 + c4]);
      Bs[row][c4] = v.x; Bs[row][c4+1] = v.y; Bs[row][c4+2] = v.z; Bs[row][c4+3] = v.w;
    }
    __syncthreads();
    #pragma unroll 8
    for (int k = 0; k < PK; k++) {
      float a8[8], b8[8];
      #pragma unroll
      for (int r = 0; r < 8; r++) a8[r] = As[mg*8+r][k];
      #pragma unroll
      for (int s = 0; s < 8; s++) b8[s] = Bs[ng*8+s][k];
      #pragma unroll
      for (int r = 0; r < 8; r++)
        #pragma unroll
        for (int s = 0; s < 8; s++) acc[r][s] += a8[r]*b8[s];
    }
    __syncthreads();
  }
  #pragma unroll
  for (int r = 0; r < 8; r++) {
    int m = m0 + mg*8 + r;
    #pragma unroll
    for (int s = 0; s < 8; s++) {
      int n = n0 + ng*8 + s;
      xw[(size_t)m*G4D + n] = acc[r][s] + b_ih[n] + b_hh[n];
    }
  }
}

// ---------------- Persistent kernel: split-flag pipeline ----------------
// flagA[blk]: partials(t) ready.  flagH[b]: h(t) ready (right after LSTM).
// flagC[b]: ctx(t) ready (after einsum).  h-side A-blocks (kc>=4) proceed on
// flagH, overlapping the B attention tail; ctx-side (kc<4) proceed on flagC.
__global__ __launch_bounds__(256) void k_persist(
    const float* __restrict__ memory, const int* __restrict__ lens,
    const float* __restrict__ W_ih, const float* __restrict__ W_hh,
    const float* __restrict__ W_g,  const float* __restrict__ b_g,
    const float* __restrict__ xw,
    float* __restrict__ h, float* __restrict__ ctxs, float* __restrict__ partial,
    int* __restrict__ flagA, int* __restrict__ flagH, int* __restrict__ flagC,
    float* __restrict__ ctx_out, float* __restrict__ align_out,
    float* __restrict__ term_out)
{
  const int blk = blockIdx.x, tid = threadIdx.x;
  const int jt = blk >> 3, kc = blk & 7;
  const int j0 = jt * JT;

  __shared__ float  Ws[JT][KC+2];     // 33.3 KB, weight-stationary
  __shared__ float4 uni4[1040];       // 16.6 KB union: Xs[32][130] | gs[2048] | wsm[1024]
  __shared__ float  hs[Dz];
  __shared__ float  cs[Dz];
  __shared__ float  phis[3*Mz], prm[3*Mz];
  __shared__ float  lom[Mz], him[Mz];
  __shared__ int    rng[2];

  float (*Xs)[KC+2] = (float(*)[KC+2])uni4;
  float* gs  = (float*)uni4;
  float* wsm = (float*)uni4;

  // stage W tile once
  {
    const float* Wsrc; int ldw, col0;
    if (kc < 4) { Wsrc = W_ih; ldw = 2*Dz; col0 = Dz + kc*KC; }   // ctx K-range
    else        { Wsrc = W_hh; ldw = Dz;   col0 = (kc-4)*KC; }    // h K-range
    for (int i = tid; i < JT*(KC/4); i += 256) {
      int jj = i >> 5, k4 = (i & 31) << 2;
      float4 v = *reinterpret_cast<const float4*>(&Wsrc[(size_t)(j0+jj)*ldw + col0 + k4]);
      Ws[jj][k4] = v.x; Ws[jj][k4+1] = v.y; Ws[jj][k4+2] = v.z; Ws[jj][k4+3] = v.w;
    }
  }
  if (blk < Bz) for (int d = tid; d < Dz; d += 256) cs[d] = 0.f;

  for (int t = 0; t < Tz; ++t) {
    // ---- wait for my K-range's producer of step t-1
    if (t > 0) {
      const int* wf = (kc >= 4) ? flagH : flagC;
      if (tid < Bz) {
        while (ld_rlx(&wf[tid*FP]) < t) __builtin_amdgcn_s_sleep(1);
      }
    }
    __syncthreads();

    // ---- stage Xs [32][128] via 8 independent 64-bit coherent loads/thread
    {
      const float* srcb = (kc < 4) ? (ctxs + kc*KC) : (h + (kc-4)*KC);
      unsigned long long xv[8];
      #pragma unroll
      for (int q = 0; q < 8; q++) {
        int f2 = (q << 8) + tid;            // 0..2047 ; 64 f2 per row
        int bb = f2 >> 6, k2 = (f2 & 63) << 1;
        xv[q] = ld_rlx64(reinterpret_cast<const unsigned long long*>(
                             srcb + (size_t)bb*Dz + k2));
      }
      #pragma unroll
      for (int q = 0; q < 8; q++) {
        int f2 = (q << 8) + tid;
        int bb = f2 >> 6, k2 = (f2 & 63) << 1;
        *reinterpret_cast<unsigned long long*>(&Xs[bb][k2]) = xv[q];
      }
    }
    __syncthreads();

    // ---- A compute: thread owns 2 j (stride 32) x 4 b
    {
      const int jg = tid & 31, bl = (tid >> 5) << 2;
      float acc[2][4] = {};
      #pragma unroll 8
      for (int k = 0; k < KC; k += 2) {
        float2 w0 = *reinterpret_cast<const float2*>(&Ws[jg][k]);
        float2 w1 = *reinterpret_cast<const float2*>(&Ws[jg+32][k]);
        #pragma unroll
        for (int bb = 0; bb < 4; bb++) {
          float2 xv = *reinterpret_cast<const float2*>(&Xs[bl+bb][k]);
          acc[0][bb] += w0.x*xv.x + w0.y*xv.y;
          acc[1][bb] += w1.x*xv.x + w1.y*xv.y;
        }
      }
      #pragma unroll
      for (int jj = 0; jj < 2; jj++)
        #pragma unroll
        for (int bb = 0; bb < 4; bb++)
          cstore(&partial[((size_t)kc*Bz + bl+bb)*G4D + j0 + jg + (jj<<5)], acc[jj][bb]);
    }
    VWAIT();                       // every thread drains own coherent stores
    __syncthreads();
    if (tid == 0) st_rlx(&flagA[blk*FP], t+1);

    // ---- B phase: blocks 0..31, one batch each
    if (blk < Bz) {
      const int b = blk;
      while (ld_rlx(&flagA[tid*FP]) < t+1) __builtin_amdgcn_s_sleep(1);
      __syncthreads();

      // reduce: gates = xw + 8 partial chunks; 64-bit loads, 8-deep pipelined
      #pragma unroll
      for (int rep = 0; rep < 4; rep++) {
        int j = ((rep << 8) + tid) << 1;
        float2 base = *reinterpret_cast<const float2*>(&xw[((size_t)b*Tz + t)*G4D + j]);
        unsigned long long pv[NKC];
        #pragma unroll
        for (int k2c = 0; k2c < NKC; k2c++)
          pv[k2c] = ld_rlx64(reinterpret_cast<const unsigned long long*>(
                                 &partial[((size_t)k2c*Bz + b)*G4D + j]));
        float sx = base.x, sy = base.y;
        #pragma unroll
        for (int k2c = 0; k2c < NKC; k2c++) {
          float2 p = unpack2(pv[k2c]);
          sx += p.x; sy += p.y;
        }
        gs[j] = sx; gs[j+1] = sy;
      }
      __syncthreads();

      // LSTM pointwise (2 consecutive d per thread), cell state in LDS
      {
        const int d0 = tid << 1;
        float i0 = 1.0f/(1.0f+expf(-gs[d0]));
        float i1 = 1.0f/(1.0f+expf(-gs[d0+1]));
        float f0 = 1.0f/(1.0f+expf(-gs[Dz+d0]));
        float f1 = 1.0f/(1.0f+expf(-gs[Dz+d0+1]));
        float g0 = tanhf(gs[2*Dz+d0]);
        float g1 = tanhf(gs[2*Dz+d0+1]);
        float o0 = 1.0f/(1.0f+expf(-gs[3*Dz+d0]));
        float o1 = 1.0f/(1.0f+expf(-gs[3*Dz+d0+1]));
        float cn0 = f0*cs[d0]   + i0*g0;
        float cn1 = f1*cs[d0+1] + i1*g1;
        float hn0 = o0*tanhf(cn0);
        float hn1 = o1*tanhf(cn1);
        cs[d0] = cn0; cs[d0+1] = cn1;
        hs[d0] = hn0; hs[d0+1] = hn1;
        st_rlx64(reinterpret_cast<unsigned long long*>(&h[b*Dz + d0]), pack2(hn0, hn1));
      }
      VWAIT();
      __syncthreads();
      if (tid == 0) st_rlx(&flagH[b*FP], t+1);   // release h-side A-blocks NOW

      // phi[m] = hs . W_g[m,:] + b_g[m]  (8 lanes/m, float4 rows)
      if (tid < 8*3*Mz) {
        int m = tid >> 3, l8 = tid & 7;
        const float4* wr = reinterpret_cast<const float4*>(W_g + m*Dz);
        const float4* hr = reinterpret_cast<const float4*>(hs);
        float s = 0.f;
        #pragma unroll
        for (int i = 0; i < 16; i++) {
          float4 wv = wr[l8 + (i<<3)];
          float4 hv = hr[l8 + (i<<3)];
          s += wv.x*hv.x + wv.y*hv.y + wv.z*hv.z + wv.w*hv.w;
        }
        s += __shfl_xor(s, 1);
        s += __shfl_xor(s, 2);
        s += __shfl_xor(s, 4);
        if (l8 == 0) phis[m] = s + b_g[m];
      }
      __syncthreads();

      // GMM params: heavy expf parallel over 10 threads, cheap tail on tid0
      if (tid < Mz) {
        float ks = expf(phis[tid]);
        float be = expf(phis[Mz + tid]);
        prm[tid]      = ks;
        prm[Mz + tid] = expf(-phis[Mz + tid]);   // 1/beta
        lom[tid] = ks - 0.5f - 25.f*be;          // sig(-25) < fp32 visibility
        him[tid] = ks + 0.5f + 25.f*be;
      }
      __syncthreads();
      if (tid == 0) {
        float mx = -1e30f;
        #pragma unroll
        for (int m = 0; m < Mz; m++) mx = fmaxf(mx, phis[2*Mz + m]);
        float ae[Mz], ssum = 0.f;
        #pragma unroll
        for (int m = 0; m < Mz; m++) { ae[m] = expf(phis[2*Mz + m] - mx); ssum += ae[m]; }
        float lo = 1e30f, hi = -1e30f;
        #pragma unroll
        for (int m = 0; m < Mz; m++) {
          prm[2*Mz + m] = ae[m] / ssum;
          lo = fminf(lo, lom[m]); hi = fmaxf(hi, him[m]);
        }
        int llo = lo > 0.f ? (int)floorf(lo) : 0;
        if (llo > Lz) llo = Lz;
        int lhi = hi < (float)Lz ? (int)ceilf(hi) + 1 : Lz;
        if (lhi > Lz) lhi = Lz;
        rng[0] = llo; rng[1] = lhi;
      }
      __syncthreads();
      const int llo = rng[0], lhi = rng[1];

      // w on active range -> LDS only (align_out deferred past flagC)
      for (int l = llo + tid; l < lhi; l += 256) {
        float u = (float)l;
        float t1 = 0.f, t0 = 0.f;
        #pragma unroll
        for (int m = 0; m < Mz; m++) {
          float ks = prm[m], ib = prm[Mz + m], al = prm[2*Mz + m];
          t1 += al * fsig((u + 0.5f - ks) * ib);
          t0 += al * fsig((u - 0.5f - ks) * ib);
        }
        wsm[l] = t1 - t0;
      }
      __syncthreads();

      // ctx einsum over active range (2 consecutive d per thread)
      {
        const int d0 = tid << 1;
        const float* mb = memory + (size_t)b*Lz*Dz + d0;
        float a0 = 0.f, a1 = 0.f;
        for (int l = llo; l < lhi; l++) {
          float w = wsm[l];
          float2 mv = *reinterpret_cast<const float2*>(&mb[(size_t)l*Dz]);
          a0 = fmaf(w, mv.x, a0);
          a1 = fmaf(w, mv.y, a1);
        }
        st_rlx64(reinterpret_cast<unsigned long long*>(&ctxs[b*Dz + d0]), pack2(a0, a1));
        if (t == Tz-1) {
          ctx_out[b*Dz + d0]     = a0;
          ctx_out[b*Dz + d0 + 1] = a1;
        }
      }
      VWAIT();
      __syncthreads();
      if (tid == 0) st_rlx(&flagC[b*FP], t+1);   // release ctx-side A-blocks

      // ---- off critical path: alignment row + termination
      for (int l = llo + tid; l < lhi; l += 256)
        align_out[((size_t)b*Tz + t)*Lz + l] = wsm[l];
      if (t == Tz-1 && tid == 0) {
        float u = (float)(lens[b] - 1);
        float t1 = 0.f;
        #pragma unroll
        for (int m = 0; m < Mz; m++)
          t1 += prm[2*Mz + m] * fsig((u + 0.5f - prm[m]) * prm[Mz + m]);
        term_out[b] = 1.0f - t1;
      }
    }
  }
}

// ================= fallback (small ws): two-kernel loop path =================
__global__ __launch_bounds__(256) void k_gemm(
    const float* __restrict__ x_all, const float* __restrict__ ctxs,
    const float* __restrict__ h, const float* __restrict__ W_ih,
    const float* __restrict__ W_hh, float* __restrict__ partial, int t, int kbase)
{
  __shared__ float Xs[Bz][KC+2];
  __shared__ float Wt[128][KC+2];
  const int jt = blockIdx.x, kcb = blockIdx.y;
  const int j0 = jt*128, k0 = kbase + kcb*KC;
  const int tid = threadIdx.x;
  for (int i = tid; i < Bz*KC; i += 256) {
    int bb = i >> 7, kk = i & (KC-1);
    int k = k0 + kk;
    float v;
    if (k < Dz)        v = x_all[((size_t)bb*Tz + t)*Dz + k];
    else if (k < 2*Dz) v = ctxs[bb*Dz + (k - Dz)];
    else               v = h[bb*Dz + (k - 2*Dz)];
    Xs[bb][kk] = v;
  }
  {
    const float* Wsrc; int ldw, col0;
    if (k0 < 2*Dz) { Wsrc = W_ih; ldw = 2*Dz; col0 = k0; }
    else           { Wsrc = W_hh; ldw = Dz;   col0 = k0 - 2*Dz; }
    for (int i = tid; i < 128*(KC/4); i += 256) {
      int jj = i >> 5, k4 = (i & 31) << 2;
      float4 v = *reinterpret_cast<const float4*>(&Wsrc[(size_t)(j0 + jj)*ldw + col0 + k4]);
      Wt[jj][k4] = v.x; Wt[jj][k4+1] = v.y; Wt[jj][k4+2] = v.z; Wt[jj][k4+3] = v.w;
    }
  }
  __syncthreads();
  const int jg = tid & 31, bg = tid >> 5;
  const int bl = bg << 2;
  float acc[4][4] = {};
  #pragma unroll 4
  for (int k = 0; k < KC; k += 2) {
    float2 xv[4], wv[4];
    #pragma unroll
    for (int bb2 = 0; bb2 < 4; bb2++)
      xv[bb2] = *reinterpret_cast<const float2*>(&Xs[bl + bb2][k]);
    #pragma unroll
    for (int jj = 0; jj < 4; jj++)
      wv[jj] = *reinterpret_cast<const float2*>(&Wt[jg + (jj << 5)][k]);
    #pragma unroll
    for (int jj = 0; jj < 4; jj++)
      #pragma unroll
      for (int bb2 = 0; bb2 < 4; bb2++)
        acc[jj][bb2] += wv[jj].x * xv[bb2].x + wv[jj].y * xv[bb2].y;
  }
  #pragma unroll
  for (int jj = 0; jj < 4; jj++)
    #pragma unroll
    for (int bb2 = 0; bb2 < 4; bb2++)
      partial[((size_t)kcb*Bz + (bl + bb2))*G4D + j0 + jg + (jj << 5)] = acc[jj][bb2];
}

__global__ __launch_bounds__(512) void k_fused(
    const float* __restrict__ partial, const float* __restrict__ b_ih,
    const float* __restrict__ b_hh,
    float* __restrict__ h, float* __restrict__ c,
    const float* __restrict__ W_g, const float* __restrict__ b_g,
    const float* __restrict__ memory, const int* __restrict__ lens,
    float* __restrict__ ctxs, float* __restrict__ ctx_out,
    float* __restrict__ align_out, float* __restrict__ term_out,
    int t, int final_, int nkc)
{
  const int b = blockIdx.x, tid = threadIdx.x;
  __shared__ float4 gs4[G4D/4];
  __shared__ float hsb[Dz];
  __shared__ float phis[3*Mz];
  __shared__ float prm[3*Mz];
  __shared__ float wsm[Lz];
  __shared__ int   rng[2];
  float* gs = (float*)gs4;
  {
    int j = 4*tid;
    float4 bi = *reinterpret_cast<const float4*>(&b_ih[j]);
    float4 bh = *reinterpret_cast<const float4*>(&b_hh[j]);
    float4 s = make_float4(bi.x+bh.x, bi.y+bh.y, bi.z+bh.z, bi.w+bh.w);
    const float4* pp = reinterpret_cast<const float4*>(partial) + (size_t)b*(G4D/4) + tid;
    for (int kcb = 0; kcb < nkc; kcb++) {
      float4 p = pp[(size_t)kcb*Bz*(G4D/4)];
      s.x += p.x; s.y += p.y; s.z += p.z; s.w += p.w;
    }
    gs4[tid] = s;
  }
  __syncthreads();
  {
    const int d = tid;
    float ig = 1.0f / (1.0f + expf(-gs[d]));
    float fg = 1.0f / (1.0f + expf(-gs[Dz + d]));
    float gg = tanhf(gs[2*Dz + d]);
    float og = 1.0f / (1.0f + expf(-gs[3*Dz + d]));
    float cn = fg * c[b*Dz + d] + ig * gg;
    float hn = og * tanhf(cn);
    c[b*Dz + d] = cn;
    h[b*Dz + d] = hn;
    hsb[d] = hn;
  }
  __syncthreads();
  if (tid < 16*3*Mz) {
    int m = tid >> 4, l16 = tid & 15;
    float s = 0.f;
    #pragma unroll 4
    for (int k = l16; k < Dz; k += 16) s += W_g[m*Dz + k] * hsb[k];
    s += __shfl_xor(s, 1);
    s += __shfl_xor(s, 2);
    s += __shfl_xor(s, 4);
    s += __shfl_xor(s, 8);
    if (l16 == 0) phis[m] = s + b_g[m];
  }
  __syncthreads();
  if (tid == 0) {
    float mx = -1e30f;
    #pragma unroll
    for (int m = 0; m < Mz; m++) mx = fmaxf(mx, phis[2*Mz + m]);
    float ae[Mz], ssum = 0.f;
    #pragma unroll
    for (int m = 0; m < Mz; m++) { ae[m] = expf(phis[2*Mz + m] - mx); ssum += ae[m]; }
    float lo = 1e30f, hi = -1e30f;
    #pragma unroll
    for (int m = 0; m < Mz; m++) {
      float ks = expf(phis[m]);
      float be = expf(phis[Mz + m]);
      prm[m]        = ks;
      prm[Mz + m]   = expf(-phis[Mz + m]);
      prm[2*Mz + m] = ae[m] / ssum;
      lo = fminf(lo, ks - 0.5f - 25.f*be);
      hi = fmaxf(hi, ks + 0.5f + 25.f*be);
    }
    int llo = lo > 0.f ? (int)floorf(lo) : 0;
    if (llo > Lz) llo = Lz;
    int lhi = hi < (float)Lz ? (int)ceilf(hi) + 1 : Lz;
    if (lhi > Lz) lhi = Lz;
    rng[0] = llo; rng[1] = lhi;
  }
  __syncthreads();
  const int llo = rng[0], lhi = rng[1];
  for (int l = llo + tid; l < lhi; l += 512) {
    float u = (float)l;
    float t1 = 0.f, t0 = 0.f;
    #pragma unroll
    for (int m = 0; m < Mz; m++) {
      float ks = prm[m], ib = prm[Mz + m], al = prm[2*Mz + m];
      t1 += al * fsig((u + 0.5f - ks) * ib);
      t0 += al * fsig((u - 0.5f - ks) * ib);
    }
    float w = t1 - t0;
    wsm[l] = w;
    align_out[((size_t)b*Tz + t)*Lz + l] = w;
  }
  __syncthreads();
  {
    const float* mb = memory + (size_t)b*Lz*Dz + tid;
    float acc = 0.f;
    #pragma unroll 4
    for (int l = llo; l < lhi; l++)
      acc += wsm[l] * mb[(size_t)l*Dz];
    ctxs[b*Dz + tid] = acc;
    if (final_) ctx_out[b*Dz + tid] = acc;
  }
  if (final_ && tid == 0) {
    float u = (float)(lens[b] - 1);
    float t1 = 0.f;
    #pragma unroll
    for (int m = 0; m < Mz; m++)
      t1 += prm[2*Mz + m] * fsig((u + 0.5f - prm[m]) * prm[Mz + m]);
    term_out[b] = 1.0f - t1;
  }
}

extern "C" void kernel_launch(void* const* d_in, const int* in_sizes, int n_in,
                              void* d_out, int out_size, void* d_ws, size_t ws_size,
                              hipStream_t stream)
{
  (void)in_sizes; (void)n_in; (void)out_size;
  const float* x    = (const float*)d_in[0];
  const float* mem  = (const float*)d_in[1];
  const int*   lens = (const int*)d_in[2];
  const float* W_ih = (const float*)d_in[3];
  const float* W_hh = (const float*)d_in[4];
  const float* b_ih = (const float*)d_in[5];
  const float* b_hh = (const float*)d_in[6];
  const float* W_g  = (const float*)d_in[7];
  const float* b_g  = (const float*)d_in[8];

  float* out = (float*)d_out;
  float* ctx_out   = out;                                  // [B,1,D]
  float* align_out = out + Bz*Dz;                          // [B,T,L]
  float* term_out  = out + Bz*Dz + (size_t)Bz*Tz*Lz;       // [B,1]

  const size_t needP = ((size_t)NFLAGS + 2*Bz*Dz + (size_t)NKC*Bz*G4D
                        + (size_t)Bz*Tz*G4D) * sizeof(float);

  hipMemsetAsync(align_out, 0, (size_t)Bz*Tz*Lz*sizeof(float), stream);

  if (ws_size >= needP) {
    int*   flags   = (int*)d_ws;
    int*   flagA   = flags;                       // [256*FP]
    int*   flagH   = flags + NFLA;                // [32*FP]
    int*   flagC   = flags + NFLA + NFLH;         // [32*FP]
    float* h       = (float*)d_ws + NFLAGS;       // [B,D]
    float* ctxs    = h + Bz*Dz;                   // [B,D]
    float* partial = ctxs + Bz*Dz;                // [8][B][4D]
    float* xw      = partial + (size_t)NKC*Bz*G4D;// [B*T][4D]

    hipMemsetAsync(d_ws, 0, (size_t)(NFLAGS + 2*Bz*Dz)*sizeof(float), stream);
    k_pre<<<dim3((Bz*Tz)/PM, G4D/PN), 256, 0, stream>>>(x, W_ih, b_ih, b_hh, xw);
    k_persist<<<NBLK, 256, 0, stream>>>(mem, lens, W_ih, W_hh, W_g, b_g, xw,
                                        h, ctxs, partial, flagA, flagH, flagC,
                                        ctx_out, align_out, term_out);
  } else {
    float* wsf     = (float*)d_ws;
    float* h       = wsf;
    float* c       = h + Bz*Dz;
    float* ctxs    = c + Bz*Dz;
    float* partial = ctxs + Bz*Dz;               // [12][B][4D]
    hipMemsetAsync(d_ws, 0, (size_t)(3*Bz*Dz)*sizeof(float), stream);
    for (int t = 0; t < Tz; t++) {
      k_gemm<<<dim3(G4D/128, 12), 256, 0, stream>>>(x, ctxs, h, W_ih, W_hh, partial, t, 0);
      k_fused<<<Bz, 512, 0, stream>>>(partial, b_ih, b_hh, h, c, W_g, b_g,
                                      mem, lens, ctxs, ctx_out, align_out, term_out,
                                      t, t == Tz-1, 12);
    }
  }
}

// Round 7
// 10104.565 us; speedup vs baseline: 8.5060x; 1.0364x over previous
//
#include <hip/hip_runtime.h>

#define Bz 32
#define Tz 512
#define Dz 512
#define Lz 1024
#define Mz 10
#define G4D 2048
#define KC 128
#define JT 64
#define NKC 8
#define NBLKA 256
#define NBLK (NBLKA + Bz)     // 288: 256 A-blocks + 32 B-blocks
#define FP 32                 // ints per flag slot (128B line padding)
#define NFLA (NBLKA*FP)       // 8192 ints
#define NFLH (Bz*FP)          // 1024 ints
#define NFLAGS (NFLA + 2*NFLH) // 10240 ints
// k_pre tiles
#define PM 128
#define PN 128
#define PK 32

__device__ __forceinline__ float fsig(float x) { return 1.0f / (1.0f + __expf(-x)); }

// ---- cross-block comm: RELAXED agent-scope atomics (sc-flagged, bypass L1/L2
// to the device coherence point; no cache-maintenance instructions) ----
__device__ __forceinline__ void st_rlx(int* p, int v) {
  __hip_atomic_store(p, v, __ATOMIC_RELAXED, __HIP_MEMORY_SCOPE_AGENT);
}
__device__ __forceinline__ int ld_rlx(const int* p) {
  return __hip_atomic_load(p, __ATOMIC_RELAXED, __HIP_MEMORY_SCOPE_AGENT);
}
__device__ __forceinline__ void st_rlx64(unsigned long long* p, unsigned long long v) {
  __hip_atomic_store(p, v, __ATOMIC_RELAXED, __HIP_MEMORY_SCOPE_AGENT);
}
__device__ __forceinline__ unsigned long long ld_rlx64(const unsigned long long* p) {
  return __hip_atomic_load(p, __ATOMIC_RELAXED, __HIP_MEMORY_SCOPE_AGENT);
}
__device__ __forceinline__ void cstore(float* p, float v) {
  __hip_atomic_store(p, v, __ATOMIC_RELAXED, __HIP_MEMORY_SCOPE_AGENT);
}
__device__ __forceinline__ unsigned long long pack2(float a, float b) {
  union { float f[2]; unsigned long long u; } z; z.f[0] = a; z.f[1] = b; return z.u;
}
__device__ __forceinline__ float2 unpack2(unsigned long long u) {
  union { unsigned long long uu; float2 f; } z; z.uu = u; return z.f;
}
#define VWAIT() asm volatile("s_waitcnt vmcnt(0)" ::: "memory")

// ---------------- K0 (once): xw[bt][j] = x[bt,:] . W_ih[j,0:512] + b_ih[j] + b_hh[j] ----------------
__global__ __launch_bounds__(256) void k_pre(
    const float* __restrict__ x, const float* __restrict__ W_ih,
    const float* __restrict__ b_ih, const float* __restrict__ b_hh,
    float* __restrict__ xw)
{
  __shared__ float As[PM][PK+1];
  __shared__ float Bs[PN][PK+1];
  const int m0 = blockIdx.x*PM, n0 = blockIdx.y*PN;
  const int tid = threadIdx.x;
  const int mg = tid >> 4, ng = tid & 15;
  float acc[8][8] = {};
  for (int k0 = 0; k0 < Dz; k0 += PK) {
    for (int i = tid; i < PM*(PK/4); i += 256) {
      int row = i >> 3, c4 = (i & 7) << 2;
      float4 v = *reinterpret_cast<const float4*>(&x[(size_t)(m0+row)*Dz + k0 + c4]);
      As[row][c4] = v.x; As[row][c4+1] = v.y; As[row][c4+2] = v.z; As[row][c4+3] = v.w;
    }
    for (int i = tid; i < PN*(PK/4); i += 256) {
      int row = i >> 3, c4 = (i & 7) << 2;
      float4 v = *reinterpret_cast<const float4*>(&W_ih[(size_t)(n0+row)*(2*Dz) + k0 + c4]);
      Bs[row][c4] = v.x; Bs[row][c4+1] = v.y; Bs[row][c4+2] = v.z; Bs[row][c4+3] = v.w;
    }
    __syncthreads();
    #pragma unroll 8
    for (int k = 0; k < PK; k++) {
      float a8[8], b8[8];
      #pragma unroll
      for (int r = 0; r < 8; r++) a8[r] = As[mg*8+r][k];
      #pragma unroll
      for (int s = 0; s < 8; s++) b8[s] = Bs[ng*8+s][k];
      #pragma unroll
      for (int r = 0; r < 8; r++)
        #pragma unroll
        for (int s = 0; s < 8; s++) acc[r][s] += a8[r]*b8[s];
    }
    __syncthreads();
  }
  #pragma unroll
  for (int r = 0; r < 8; r++) {
    int m = m0 + mg*8 + r;
    #pragma unroll
    for (int s = 0; s < 8; s++) {
      int n = n0 + ng*8 + s;
      xw[(size_t)m*G4D + n] = acc[r][s] + b_ih[n] + b_hh[n];
    }
  }
}

// ---------------- Persistent kernel: dedicated A/B roles ----------------
// blocks 0..255: A (gates GEMM partials, jt=blk>>3, kc=blk&7).
// blocks 256..287: B (per-batch reduce+LSTM+GMM+attention tail).
// flagA[blk]: partials(t) ready. flagH[b]: h(t) ready. flagC[b]: ctx(t) ready.
__global__ __launch_bounds__(512, 4) void k_persist(
    const float* __restrict__ memory, const int* __restrict__ lens,
    const float* __restrict__ W_ih, const float* __restrict__ W_hh,
    const float* __restrict__ W_g,  const float* __restrict__ b_g,
    const float* __restrict__ xw,
    float* __restrict__ h, float* __restrict__ ctxs, float* __restrict__ partial,
    int* __restrict__ flagA, int* __restrict__ flagH, int* __restrict__ flagC,
    float* __restrict__ ctx_out, float* __restrict__ align_out,
    float* __restrict__ term_out)
{
  const int blk = blockIdx.x, tid = threadIdx.x;

  // 50.2 KB overlay: A uses Ws[64][130]+Xs[32][130]; B uses gs|wsm|hs|cs|part
  __shared__ __align__(16) char smem[50240];
  __shared__ float phis[3*Mz], prm[3*Mz];
  __shared__ float lom[Mz], him[Mz];
  __shared__ int   rng[2];

  if (blk < NBLKA) {
    // ================= A role =================
    const int jt = blk >> 3, kc = blk & 7;
    const int j0 = jt * JT;
    float (*Ws)[KC+2] = reinterpret_cast<float(*)[KC+2]>(smem);            // 64x130
    float (*Xs)[KC+2] = reinterpret_cast<float(*)[KC+2]>(smem + 33280);    // 32x130

    // stage W tile once (weight-stationary)
    {
      const float* Wsrc; int ldw, col0;
      if (kc < 4) { Wsrc = W_ih; ldw = 2*Dz; col0 = Dz + kc*KC; }   // ctx K-range
      else        { Wsrc = W_hh; ldw = Dz;   col0 = (kc-4)*KC; }    // h K-range
      for (int i = tid; i < JT*(KC/4); i += 512) {
        int jj = i >> 5, k4 = (i & 31) << 2;
        float4 v = *reinterpret_cast<const float4*>(&Wsrc[(size_t)(j0+jj)*ldw + col0 + k4]);
        Ws[jj][k4] = v.x; Ws[jj][k4+1] = v.y; Ws[jj][k4+2] = v.z; Ws[jj][k4+3] = v.w;
      }
    }

    for (int t = 0; t < Tz; ++t) {
      if (t > 0) {
        const int* wf = (kc >= 4) ? flagH : flagC;
        if (tid < Bz) {
          while (ld_rlx(&wf[tid*FP]) < t) __builtin_amdgcn_s_sleep(1);
        }
      }
      __syncthreads();

      // stage Xs [32][128]: 4 x 64-bit coherent loads/thread
      {
        const float* srcb = (kc < 4) ? (ctxs + kc*KC) : (h + (kc-4)*KC);
        unsigned long long xv[4];
        #pragma unroll
        for (int q = 0; q < 4; q++) {
          int f2 = (q << 9) + tid;            // 0..2047
          int bb = f2 >> 6, k2 = (f2 & 63) << 1;
          xv[q] = ld_rlx64(reinterpret_cast<const unsigned long long*>(
                               srcb + (size_t)bb*Dz + k2));
        }
        #pragma unroll
        for (int q = 0; q < 4; q++) {
          int f2 = (q << 9) + tid;
          int bb = f2 >> 6, k2 = (f2 & 63) << 1;
          *reinterpret_cast<unsigned long long*>(&Xs[bb][k2]) = xv[q];
        }
      }
      __syncthreads();

      // A compute: thread owns 1 j x 4 b
      {
        const int jg = tid & 63, bl = (tid >> 6) << 2;
        float acc[4] = {};
        #pragma unroll 8
        for (int k = 0; k < KC; k += 2) {
          float2 w0 = *reinterpret_cast<const float2*>(&Ws[jg][k]);
          #pragma unroll
          for (int bb = 0; bb < 4; bb++) {
            float2 xv = *reinterpret_cast<const float2*>(&Xs[bl+bb][k]);
            acc[bb] += w0.x*xv.x + w0.y*xv.y;
          }
        }
        #pragma unroll
        for (int bb = 0; bb < 4; bb++)
          cstore(&partial[((size_t)kc*Bz + bl+bb)*G4D + j0 + jg], acc[bb]);
      }
      VWAIT();
      __syncthreads();
      if (tid == 0) st_rlx(&flagA[blk*FP], t+1);
    }
    return;
  }

  // ================= B role =================
  const int b = blk - NBLKA;
  float* gs  = reinterpret_cast<float*>(smem);            // 2048
  float* wsm = reinterpret_cast<float*>(smem + 8192);     // 1024
  float* hs  = reinterpret_cast<float*>(smem + 12288);    // 512
  float* cs  = reinterpret_cast<float*>(smem + 14336);    // 512
  float (*part)[Dz] = reinterpret_cast<float(*)[Dz]>(smem + 16384); // 8x512

  cs[tid] = 0.f;

  for (int t = 0; t < Tz; ++t) {
    if (tid < NBLKA) {
      while (ld_rlx(&flagA[tid*FP]) < t+1) __builtin_amdgcn_s_sleep(1);
    }
    __syncthreads();

    // reduce: gates = xw + 8 partial chunks (64-bit coherent loads, pipelined)
    #pragma unroll
    for (int rep = 0; rep < 2; rep++) {
      int j = ((rep << 9) + tid) << 1;
      float2 base = *reinterpret_cast<const float2*>(&xw[((size_t)b*Tz + t)*G4D + j]);
      unsigned long long pv[NKC];
      #pragma unroll
      for (int k2c = 0; k2c < NKC; k2c++)
        pv[k2c] = ld_rlx64(reinterpret_cast<const unsigned long long*>(
                               &partial[((size_t)k2c*Bz + b)*G4D + j]));
      float sx = base.x, sy = base.y;
      #pragma unroll
      for (int k2c = 0; k2c < NKC; k2c++) {
        float2 p = unpack2(pv[k2c]);
        sx += p.x; sy += p.y;
      }
      gs[j] = sx; gs[j+1] = sy;
    }
    __syncthreads();

    // LSTM pointwise (1 d per thread), cell state in LDS
    {
      const int d = tid;
      float ig = 1.0f/(1.0f+expf(-gs[d]));
      float fg = 1.0f/(1.0f+expf(-gs[Dz+d]));
      float gg = tanhf(gs[2*Dz+d]);
      float og = 1.0f/(1.0f+expf(-gs[3*Dz+d]));
      float cn = fg*cs[d] + ig*gg;
      float hn = og*tanhf(cn);
      cs[d] = cn; hs[d] = hn;
      cstore(&h[b*Dz + d], hn);
    }
    VWAIT();
    __syncthreads();
    if (tid == 0) st_rlx(&flagH[b*FP], t+1);   // release h-side A-blocks NOW

    // phi[m] = hs . W_g[m,:] + b_g[m]  (16 lanes/m, float4 rows)
    if (tid < 16*3*Mz) {
      int m = tid >> 4, l16 = tid & 15;
      const float4* wr = reinterpret_cast<const float4*>(W_g + m*Dz);
      const float4* hr = reinterpret_cast<const float4*>(hs);
      float s = 0.f;
      #pragma unroll
      for (int i = 0; i < 8; i++) {
        float4 wv = wr[l16 + (i<<4)];
        float4 hv = hr[l16 + (i<<4)];
        s += wv.x*hv.x + wv.y*hv.y + wv.z*hv.z + wv.w*hv.w;
      }
      s += __shfl_xor(s, 1);
      s += __shfl_xor(s, 2);
      s += __shfl_xor(s, 4);
      s += __shfl_xor(s, 8);
      if (l16 == 0) phis[m] = s + b_g[m];
    }
    __syncthreads();

    // GMM params: heavy expf parallel over 10 threads, cheap tail on tid0
    if (tid < Mz) {
      float ks = expf(phis[tid]);
      float be = expf(phis[Mz + tid]);
      prm[tid]      = ks;
      prm[Mz + tid] = expf(-phis[Mz + tid]);   // 1/beta
      lom[tid] = ks - 0.5f - 25.f*be;          // sig(-25) < fp32 visibility
      him[tid] = ks + 0.5f + 25.f*be;
    }
    __syncthreads();
    if (tid == 0) {
      float mx = -1e30f;
      #pragma unroll
      for (int m = 0; m < Mz; m++) mx = fmaxf(mx, phis[2*Mz + m]);
      float ae[Mz], ssum = 0.f;
      #pragma unroll
      for (int m = 0; m < Mz; m++) { ae[m] = expf(phis[2*Mz + m] - mx); ssum += ae[m]; }
      float lo = 1e30f, hi = -1e30f;
      #pragma unroll
      for (int m = 0; m < Mz; m++) {
        prm[2*Mz + m] = ae[m] / ssum;
        lo = fminf(lo, lom[m]); hi = fmaxf(hi, him[m]);
      }
      int llo = lo > 0.f ? (int)floorf(lo) : 0;
      if (llo > Lz) llo = Lz;
      int lhi = hi < (float)Lz ? (int)ceilf(hi) + 1 : Lz;
      if (lhi > Lz) lhi = Lz;
      rng[0] = llo; rng[1] = lhi;
    }
    __syncthreads();
    const int llo = rng[0], lhi = rng[1];

    // w on active range (LDS only; align_out deferred past flagC)
    for (int l = llo + tid; l < lhi; l += 512) {
      float u = (float)l;
      float t1 = 0.f, t0 = 0.f;
      #pragma unroll
      for (int m = 0; m < Mz; m++) {
        float ks = prm[m], ib = prm[Mz + m], al = prm[2*Mz + m];
        t1 += al * fsig((u + 0.5f - ks) * ib);
        t0 += al * fsig((u - 0.5f - ks) * ib);
      }
      wsm[l] = t1 - t0;
    }
    __syncthreads();

    // ctx einsum: 8 waves split the l-range; lane owns 8 consecutive d
    {
      const int wv = tid >> 6, lane = tid & 63, d0 = lane << 3;
      const int range = lhi - llo;
      const int chunk = (range + 7) >> 3;
      const int lbeg = llo + wv*chunk;
      const int lend = (lbeg + chunk < lhi) ? lbeg + chunk : lhi;
      const float* mb = memory + (size_t)b*Lz*Dz + d0;
      float4 a0 = make_float4(0.f,0.f,0.f,0.f), a1 = a0;
      #pragma unroll 2
      for (int l = lbeg; l < lend; l++) {
        float w = wsm[l];
        float4 m0 = *reinterpret_cast<const float4*>(&mb[(size_t)l*Dz]);
        float4 m1 = *reinterpret_cast<const float4*>(&mb[(size_t)l*Dz + 4]);
        a0.x = fmaf(w, m0.x, a0.x); a0.y = fmaf(w, m0.y, a0.y);
        a0.z = fmaf(w, m0.z, a0.z); a0.w = fmaf(w, m0.w, a0.w);
        a1.x = fmaf(w, m1.x, a1.x); a1.y = fmaf(w, m1.y, a1.y);
        a1.z = fmaf(w, m1.z, a1.z); a1.w = fmaf(w, m1.w, a1.w);
      }
      *reinterpret_cast<float4*>(&part[wv][d0])     = a0;
      *reinterpret_cast<float4*>(&part[wv][d0 + 4]) = a1;
    }
    __syncthreads();
    {
      const int d = tid;
      float s = part[0][d] + part[1][d] + part[2][d] + part[3][d]
              + part[4][d] + part[5][d] + part[6][d] + part[7][d];
      cstore(&ctxs[b*Dz + d], s);
      if (t == Tz-1) ctx_out[b*Dz + d] = s;
    }
    VWAIT();
    __syncthreads();
    if (tid == 0) st_rlx(&flagC[b*FP], t+1);   // release ctx-side A-blocks

    // off critical path: alignment row + termination
    for (int l = llo + tid; l < lhi; l += 512)
      align_out[((size_t)b*Tz + t)*Lz + l] = wsm[l];
    if (t == Tz-1 && tid == 0) {
      float u = (float)(lens[b] - 1);
      float t1 = 0.f;
      #pragma unroll
      for (int m = 0; m < Mz; m++)
        t1 += prm[2*Mz + m] * fsig((u + 0.5f - prm[m]) * prm[Mz + m]);
      term_out[b] = 1.0f - t1;
    }
  }
}

// ================= fallback (small ws): two-kernel loop path =================
__global__ __launch_bounds__(256) void k_gemm(
    const float* __restrict__ x_all, const float* __restrict__ ctxs,
    const float* __restrict__ h, const float* __restrict__ W_ih,
    const float* __restrict__ W_hh, float* __restrict__ partial, int t, int kbase)
{
  __shared__ float Xs[Bz][KC+2];
  __shared__ float Wt[128][KC+2];
  const int jt = blockIdx.x, kcb = blockIdx.y;
  const int j0 = jt*128, k0 = kbase + kcb*KC;
  const int tid = threadIdx.x;
  for (int i = tid; i < Bz*KC; i += 256) {
    int bb = i >> 7, kk = i & (KC-1);
    int k = k0 + kk;
    float v;
    if (k < Dz)        v = x_all[((size_t)bb*Tz + t)*Dz + k];
    else if (k < 2*Dz) v = ctxs[bb*Dz + (k - Dz)];
    else               v = h[bb*Dz + (k - 2*Dz)];
    Xs[bb][kk] = v;
  }
  {
    const float* Wsrc; int ldw, col0;
    if (k0 < 2*Dz) { Wsrc = W_ih; ldw = 2*Dz; col0 = k0; }
    else           { Wsrc = W_hh; ldw = Dz;   col0 = k0 - 2*Dz; }
    for (int i = tid; i < 128*(KC/4); i += 256) {
      int jj = i >> 5, k4 = (i & 31) << 2;
      float4 v = *reinterpret_cast<const float4*>(&Wsrc[(size_t)(j0 + jj)*ldw + col0 + k4]);
      Wt[jj][k4] = v.x; Wt[jj][k4+1] = v.y; Wt[jj][k4+2] = v.z; Wt[jj][k4+3] = v.w;
    }
  }
  __syncthreads();
  const int jg = tid & 31, bg = tid >> 5;
  const int bl = bg << 2;
  float acc[4][4] = {};
  #pragma unroll 4
  for (int k = 0; k < KC; k += 2) {
    float2 xv[4], wv[4];
    #pragma unroll
    for (int bb2 = 0; bb2 < 4; bb2++)
      xv[bb2] = *reinterpret_cast<const float2*>(&Xs[bl + bb2][k]);
    #pragma unroll
    for (int jj = 0; jj < 4; jj++)
      wv[jj] = *reinterpret_cast<const float2*>(&Wt[jg + (jj << 5)][k]);
    #pragma unroll
    for (int jj = 0; jj < 4; jj++)
      #pragma unroll
      for (int bb2 = 0; bb2 < 4; bb2++)
        acc[jj][bb2] += wv[jj].x * xv[bb2].x + wv[jj].y * xv[bb2].y;
  }
  #pragma unroll
  for (int jj = 0; jj < 4; jj++)
    #pragma unroll
    for (int bb2 = 0; bb2 < 4; bb2++)
      partial[((size_t)kcb*Bz + (bl + bb2))*G4D + j0 + jg + (jj << 5)] = acc[jj][bb2];
}

__global__ __launch_bounds__(512) void k_fused(
    const float* __restrict__ partial, const float* __restrict__ b_ih,
    const float* __restrict__ b_hh,
    float* __restrict__ h, float* __restrict__ c,
    const float* __restrict__ W_g, const float* __restrict__ b_g,
    const float* __restrict__ memory, const int* __restrict__ lens,
    float* __restrict__ ctxs, float* __restrict__ ctx_out,
    float* __restrict__ align_out, float* __restrict__ term_out,
    int t, int final_, int nkc)
{
  const int b = blockIdx.x, tid = threadIdx.x;
  __shared__ float4 gs4[G4D/4];
  __shared__ float hsb[Dz];
  __shared__ float phis[3*Mz];
  __shared__ float prm[3*Mz];
  __shared__ float wsm[Lz];
  __shared__ int   rng[2];
  float* gs = (float*)gs4;
  {
    int j = 4*tid;
    float4 bi = *reinterpret_cast<const float4*>(&b_ih[j]);
    float4 bh = *reinterpret_cast<const float4*>(&b_hh[j]);
    float4 s = make_float4(bi.x+bh.x, bi.y+bh.y, bi.z+bh.z, bi.w+bh.w);
    const float4* pp = reinterpret_cast<const float4*>(partial) + (size_t)b*(G4D/4) + tid;
    for (int kcb = 0; kcb < nkc; kcb++) {
      float4 p = pp[(size_t)kcb*Bz*(G4D/4)];
      s.x += p.x; s.y += p.y; s.z += p.z; s.w += p.w;
    }
    gs4[tid] = s;
  }
  __syncthreads();
  {
    const int d = tid;
    float ig = 1.0f / (1.0f + expf(-gs[d]));
    float fg = 1.0f / (1.0f + expf(-gs[Dz + d]));
    float gg = tanhf(gs[2*Dz + d]);
    float og = 1.0f / (1.0f + expf(-gs[3*Dz + d]));
    float cn = fg * c[b*Dz + d] + ig * gg;
    float hn = og * tanhf(cn);
    c[b*Dz + d] = cn;
    h[b*Dz + d] = hn;
    hsb[d] = hn;
  }
  __syncthreads();
  if (tid < 16*3*Mz) {
    int m = tid >> 4, l16 = tid & 15;
    float s = 0.f;
    #pragma unroll 4
    for (int k = l16; k < Dz; k += 16) s += W_g[m*Dz + k] * hsb[k];
    s += __shfl_xor(s, 1);
    s += __shfl_xor(s, 2);
    s += __shfl_xor(s, 4);
    s += __shfl_xor(s, 8);
    if (l16 == 0) phis[m] = s + b_g[m];
  }
  __syncthreads();
  if (tid == 0) {
    float mx = -1e30f;
    #pragma unroll
    for (int m = 0; m < Mz; m++) mx = fmaxf(mx, phis[2*Mz + m]);
    float ae[Mz], ssum = 0.f;
    #pragma unroll
    for (int m = 0; m < Mz; m++) { ae[m] = expf(phis[2*Mz + m] - mx); ssum += ae[m]; }
    float lo = 1e30f, hi = -1e30f;
    #pragma unroll
    for (int m = 0; m < Mz; m++) {
      float ks = expf(phis[m]);
      float be = expf(phis[Mz + m]);
      prm[m]        = ks;
      prm[Mz + m]   = expf(-phis[Mz + m]);
      prm[2*Mz + m] = ae[m] / ssum;
      lo = fminf(lo, ks - 0.5f - 25.f*be);
      hi = fmaxf(hi, ks + 0.5f + 25.f*be);
    }
    int llo = lo > 0.f ? (int)floorf(lo) : 0;
    if (llo > Lz) llo = Lz;
    int lhi = hi < (float)Lz ? (int)ceilf(hi) + 1 : Lz;
    if (lhi > Lz) lhi = Lz;
    rng[0] = llo; rng[1] = lhi;
  }
  __syncthreads();
  const int llo = rng[0], lhi = rng[1];
  for (int l = llo + tid; l < lhi; l += 512) {
    float u = (float)l;
    float t1 = 0.f, t0 = 0.f;
    #pragma unroll
    for (int m = 0; m < Mz; m++) {
      float ks = prm[m], ib = prm[Mz + m], al = prm[2*Mz + m];
      t1 += al * fsig((u + 0.5f - ks) * ib);
      t0 += al * fsig((u - 0.5f - ks) * ib);
    }
    float w = t1 - t0;
    wsm[l] = w;
    align_out[((size_t)b*Tz + t)*Lz + l] = w;
  }
  __syncthreads();
  {
    const float* mb = memory + (size_t)b*Lz*Dz + tid;
    float acc = 0.f;
    #pragma unroll 4
    for (int l = llo; l < lhi; l++)
      acc += wsm[l] * mb[(size_t)l*Dz];
    ctxs[b*Dz + tid] = acc;
    if (final_) ctx_out[b*Dz + tid] = acc;
  }
  if (final_ && tid == 0) {
    float u = (float)(lens[b] - 1);
    float t1 = 0.f;
    #pragma unroll
    for (int m = 0; m < Mz; m++)
      t1 += prm[2*Mz + m] * fsig((u + 0.5f - prm[m]) * prm[Mz + m]);
    term_out[b] = 1.0f - t1;
  }
}

extern "C" void kernel_launch(void* const* d_in, const int* in_sizes, int n_in,
                              void* d_out, int out_size, void* d_ws, size_t ws_size,
                              hipStream_t stream)
{
  (void)in_sizes; (void)n_in; (void)out_size;
  const float* x    = (const float*)d_in[0];
  const float* mem  = (const float*)d_in[1];
  const int*   lens = (const int*)d_in[2];
  const float* W_ih = (const float*)d_in[3];
  const float* W_hh = (const float*)d_in[4];
  const float* b_ih = (const float*)d_in[5];
  const float* b_hh = (const float*)d_in[6];
  const float* W_g  = (const float*)d_in[7];
  const float* b_g  = (const float*)d_in[8];

  float* out = (float*)d_out;
  float* ctx_out   = out;                                  // [B,1,D]
  float* align_out = out + Bz*Dz;                          // [B,T,L]
  float* term_out  = out + Bz*Dz + (size_t)Bz*Tz*Lz;       // [B,1]

  const size_t needP = ((size_t)NFLAGS + 2*Bz*Dz + (size_t)NKC*Bz*G4D
                        + (size_t)Bz*Tz*G4D) * sizeof(float);

  hipMemsetAsync(align_out, 0, (size_t)Bz*Tz*Lz*sizeof(float), stream);

  if (ws_size >= needP) {
    int*   flags   = (int*)d_ws;
    int*   flagA   = flags;                       // [256*FP]
    int*   flagH   = flags + NFLA;                // [32*FP]
    int*   flagC   = flags + NFLA + NFLH;         // [32*FP]
    float* h       = (float*)d_ws + NFLAGS;       // [B,D]
    float* ctxs    = h + Bz*Dz;                   // [B,D]
    float* partial = ctxs + Bz*Dz;                // [8][B][4D]
    float* xw      = partial + (size_t)NKC*Bz*G4D;// [B*T][4D]

    hipMemsetAsync(d_ws, 0, (size_t)(NFLAGS + 2*Bz*Dz)*sizeof(float), stream);
    k_pre<<<dim3((Bz*Tz)/PM, G4D/PN), 256, 0, stream>>>(x, W_ih, b_ih, b_hh, xw);
    k_persist<<<NBLK, 512, 0, stream>>>(mem, lens, W_ih, W_hh, W_g, b_g, xw,
                                        h, ctxs, partial, flagA, flagH, flagC,
                                        ctx_out, align_out, term_out);
  } else {
    float* wsf     = (float*)d_ws;
    float* h       = wsf;
    float* c       = h + Bz*Dz;
    float* ctxs    = c + Bz*Dz;
    float* partial = ctxs + Bz*Dz;               // [12][B][4D]
    hipMemsetAsync(d_ws, 0, (size_t)(3*Bz*Dz)*sizeof(float), stream);
    for (int t = 0; t < Tz; t++) {
      k_gemm<<<dim3(G4D/128, 12), 256, 0, stream>>>(x, ctxs, h, W_ih, W_hh, partial, t, 0);
      k_fused<<<Bz, 512, 0, stream>>>(partial, b_ih, b_hh, h, c, W_g, b_g,
                                      mem, lens, ctxs, ctx_out, align_out, term_out,
                                      t, t == Tz-1, 12);
    }
  }
}